// Round 7
// baseline (953.407 us; speedup 1.0000x reference)
//
#include <hip/hip_runtime.h>
#include <hip/hip_fp16.h>
#include <hip/hip_fp8.h>

namespace {

constexpr int kUsers = 100000;
constexpr int kItems = 200000;
constexpr int kN     = kUsers + kItems;   // 300000
constexpr int kD     = 64;
constexpr int kNNZ   = 5000000;
constexpr int kB     = 16384;
constexpr int kRowsPerBkt = 2048;                       // rows per coarse bucket
constexpr int kNBKT  = (kN + kRowsPerBkt - 1) / kRowsPerBkt;  // 147
constexpr int kSEPB  = 4096;                            // edges per bucket_scatter block
constexpr int kCE    = 8192;                            // edges per place chunk
constexpr int kMC    = 5;                               // chunks per bucket
constexpr int kCap   = kMC * kCE;                       // 40960 slots/bucket (mean 34133, sd 185)
constexpr int kMaxSub = 2 * kB;                         // upper bound on marked rows

typedef int   v2i __attribute__((ext_vector_type(2)));
typedef float v4f __attribute__((ext_vector_type(4)));

// --- fp8 e4m3 storage: buffers hold 64*true_value (keeps x in e4m3 normal
// range). Decode: native v_cvt_pk_f32_fp8 where available (2 ops/word vs ~8
// for the bit-trick) -> round-3 post-mortem showed decode VALU (71% busy) was
// throttling the fetch pipe; round-6 confirmed (VALUBusy 46%, dur -15%).
// Bit-trick fallback yields stored/256, patched by kValScale on the edge
// weight. NOTE: builtins return PLAIN float vectors -> index with [].
#if defined(__has_builtin)
#if __has_builtin(__builtin_amdgcn_cvt_pk_f32_fp8) && __has_builtin(__builtin_amdgcn_cvt_f32_fp8)
#define NATIVE_FP8 1
#endif
#endif
#ifndef NATIVE_FP8
#define NATIVE_FP8 0
#endif

constexpr float kValScale = NATIVE_FP8 ? 1.0f : 256.0f;

__device__ inline void dec8(v2i h, float* f) {
#if NATIVE_FP8
  auto a0 = __builtin_amdgcn_cvt_pk_f32_fp8(h.x, false);
  auto a1 = __builtin_amdgcn_cvt_pk_f32_fp8(h.x, true);
  auto a2 = __builtin_amdgcn_cvt_pk_f32_fp8(h.y, false);
  auto a3 = __builtin_amdgcn_cvt_pk_f32_fp8(h.y, true);
  f[0] = a0[0]; f[1] = a0[1]; f[2] = a1[0]; f[3] = a1[1];
  f[4] = a2[0]; f[5] = a2[1]; f[6] = a3[0]; f[7] = a3[1];
#else
  unsigned int ws[2] = {(unsigned int)h.x, (unsigned int)h.y};
#pragma unroll
  for (int q = 0; q < 2; ++q) {
    unsigned int w = ws[q];
    unsigned int a = ((w & 0x007f007fu) << 7) | ((w & 0x00800080u) << 8);
    unsigned int b = (((w >> 8) & 0x007f007fu) << 7) | (((w >> 8) & 0x00800080u) << 8);
    float2 e = __half22float2(*reinterpret_cast<const __half2*>(&a));
    float2 o = __half22float2(*reinterpret_cast<const __half2*>(&b));
    f[4 * q + 0] = e.x; f[4 * q + 1] = o.x; f[4 * q + 2] = e.y; f[4 * q + 3] = o.y;
  }
#endif
}

__device__ inline float dec1(unsigned char b) {  // stored(=64*true) -> true
#if NATIVE_FP8
  return __builtin_amdgcn_cvt_f32_fp8((int)b, 0) * 0.015625f;
#else
  unsigned int hb = ((b & 0x7fu) << 7) | ((b & 0x80u) << 8);
  return __half2float(__ushort_as_half((unsigned short)hb)) * 4.0f;
#endif
}

__device__ inline unsigned char enc(float f) { __hip_fp8_e4m3 q(f); return q.__x; }

// packed edge: bits[18:0] = col, bits[31:19] = val13 (fp16 bits rounded to
// 5-exp + 8-mantissa; vals >= 0 so no sign bit). rel err 2^-9.
__device__ inline float vdec(int w) {
  return __half2float(__ushort_as_half((unsigned short)((w >> 17) & 0x7FFC))) * kValScale;
}

__global__ void zero4(int* __restrict__ gpos, int* __restrict__ mark,
                      int* __restrict__ rowcnt, int* __restrict__ dh,
                      int* __restrict__ scnt) {
  int i = blockIdx.x * blockDim.x + threadIdx.x;
  if (i < kN) { mark[i] = 0; rowcnt[i] = 0; }
  if (i < kNBKT + 1) gpos[i] = 0;
  if (i < 64) dh[i] = 0;   // dh DEDICATED (round-5: aliasing partials -> OOB)
  if (i == 0) scnt[0] = 0;
}

// Counting-sort partition of 4096 edges into 147 coarse buckets; per-wave LDS
// histograms (4x147) cut same-address atomic serialization 4x. LDS staging so
// tmp writes go out in coalesced bucket-run bursts. Round-7: also fuses the
// per-ROW histogram here (global atomicAdd into 1.2 MB L2-resident rowcnt),
// deleting the chunk_hist pass + ctab entirely. tmp split into 4 B payload +
// 2 B rowlocal (6 B/edge, was 8). tmp read once later -> plain stores.
__global__ void bucket_scatter(const int* __restrict__ row, const int* __restrict__ col,
                               const float* __restrict__ val, int* __restrict__ gpos,
                               int* __restrict__ rowcnt, int* __restrict__ tmp4,
                               unsigned short* __restrict__ tmpr) {
  __shared__ int hcnt[4][kNBKT];   // per-wave counts -> wave-exclusive offsets
  __shared__ int lofs[kNBKT];
  __shared__ int hbase[kNBKT];
  __shared__ int lds[256];
  __shared__ int sp[kSEPB];              // payload stage
  __shared__ unsigned short sr[kSEPB];   // rowlocal stage
  __shared__ unsigned short sb[kSEPB];   // bucket stage
  int t = threadIdx.x;
  int wv = t >> 6;
  long base = (long)blockIdx.x * kSEPB;
  int valid = (int)min((long)kSEPB, (long)kNNZ - base);
  for (int i = t; i < kNBKT; i += 256) {
    hcnt[0][i] = 0; hcnt[1][i] = 0; hcnt[2][i] = 0; hcnt[3][i] = 0;
  }
  __syncthreads();
  int py[16], bk[16], rl[16], rk[16];
  bool ok[16];
#pragma unroll
  for (int j = 0; j < 16; ++j) {
    long i = base + j * 256 + t;
    ok[j] = (i < kNNZ);
    if (ok[j]) {
      int r = __builtin_nontemporal_load(row + i);
      int c = __builtin_nontemporal_load(col + i);
      float v = __builtin_nontemporal_load(val + i);
      bk[j] = r >> 11;
      rl[j] = r & 2047;
      unsigned short hb = __half_as_ushort(__float2half_rn(v));
      int v13 = ((int)hb + 2) >> 2;              // round to exp5+man8
      py[j] = c | (v13 << 19);
      rk[j] = atomicAdd(&hcnt[wv][bk[j]], 1);
      atomicAdd(&rowcnt[r], 1);                  // fused row histogram
    }
  }
  __syncthreads();
  int own = 0;
  if (t < kNBKT) {
    int c0 = hcnt[0][t], c1 = hcnt[1][t], c2 = hcnt[2][t], c3 = hcnt[3][t];
    hcnt[0][t] = 0; hcnt[1][t] = c0; hcnt[2][t] = c0 + c1; hcnt[3][t] = c0 + c1 + c2;
    own = c0 + c1 + c2 + c3;
  }
  lds[t] = own;
  __syncthreads();
  for (int o = 1; o < 256; o <<= 1) {
    int x = (t >= o) ? lds[t - o] : 0;
    __syncthreads();
    if (t >= o) lds[t] += x;
    __syncthreads();
  }
  if (t < kNBKT) {
    lofs[t] = lds[t] - own;
    hbase[t] = t * kCap + atomicAdd(&gpos[t], own);
  }
  __syncthreads();
#pragma unroll
  for (int j = 0; j < 16; ++j) {
    if (ok[j]) {
      int pos = lofs[bk[j]] + hcnt[wv][bk[j]] + rk[j];
      sp[pos] = py[j];
      sr[pos] = (unsigned short)rl[j];
      sb[pos] = (unsigned short)bk[j];
    }
  }
  __syncthreads();
#pragma unroll
  for (int j = 0; j < 16; ++j) {
    int pos = t + j * 256;
    if (pos < valid) {
      int b = sb[pos];
      int w = hbase[b] + (pos - lofs[b]);
      tmp4[w] = sp[pos];
      tmpr[w] = sr[pos];
    }
  }
}

// 147 blocks: block-scan 2048 row counts -> bucket-local rowptr + partial.
__global__ void scanR(const int* __restrict__ rowcnt, int* __restrict__ rowptr,
                      int* __restrict__ partials) {
  __shared__ int lsum[256];
  int b = blockIdx.x, t = threadIdx.x;
  int cnt[8];
#pragma unroll
  for (int k = 0; k < 8; ++k) {
    int idx = b * kRowsPerBkt + t * 8 + k;
    cnt[k] = (idx < kN) ? rowcnt[idx] : 0;
  }
  int s = 0, pref[8];
#pragma unroll
  for (int k = 0; k < 8; ++k) { pref[k] = s; s += cnt[k]; }
  lsum[t] = s;
  __syncthreads();
  for (int o = 1; o < 256; o <<= 1) {
    int v = (t >= o) ? lsum[t - o] : 0;
    __syncthreads();
    if (t >= o) lsum[t] += v;
    __syncthreads();
  }
  int ex = (t == 0) ? 0 : lsum[t - 1];
#pragma unroll
  for (int k = 0; k < 8; ++k) {
    int r = b * kRowsPerBkt + t * 8 + k;
    if (r < kN) rowptr[r] = ex + pref[k];
  }
  if (t == 255) partials[b] = lsum[255];
}

__global__ void scan2(int* __restrict__ partials) {
  __shared__ int lds[256];
  int t = threadIdx.x;
  lds[t] = (t < kNBKT) ? partials[t] : 0;
  __syncthreads();
  for (int o = 1; o < 256; o <<= 1) {
    int v = (t >= o) ? lds[t - o] : 0;
    __syncthreads();
    if (t >= o) lds[t] += v;
    __syncthreads();
  }
  int ex = (t == 0) ? 0 : lds[t - 1];
  if (t < kNBKT) partials[t] = ex;
}

// Finalize rowptr and initialize the placement cursors (rowcur aliases the
// rowcnt buffer: rowcnt's last read was scanR).
__global__ void scan3(int* __restrict__ rowptr, const int* __restrict__ partials,
                      int* __restrict__ rowcur) {
  int i = blockIdx.x * blockDim.x + threadIdx.x;
  if (i < kN) {
    int v = rowptr[i] + partials[i >> 11];
    rowptr[i] = v;
    rowcur[i] = v;
  } else if (i == kN) {
    rowptr[kN] = kNNZ;
  }
}

// Grid = kNBKT*kMC. Place edges to final CSR slots via global row cursors
// (1.2 MB L2-resident). Random 4 B writes confined to the bucket's ~136 KB
// edges window; within-row order nondeterministic (was already, via LDS rank).
__global__ void place(const int* __restrict__ gpos, const int* __restrict__ tmp4,
                      const unsigned short* __restrict__ tmpr,
                      int* __restrict__ rowcur, int* __restrict__ edges) {
  int b = blockIdx.x / kMC, c = blockIdx.x % kMC;
  int t = threadIdx.x;
  int s = b * kCap + c * kCE;
  int e = b * kCap + gpos[b];
  if (s + kCE < e) e = s + kCE;
  for (int j = s + t; j < e; j += 256) {
    int pay = tmp4[j];
    int r = b * kRowsPerBkt + (int)tmpr[j];
    int dst = atomicAdd(&rowcur[r], 1);
    edges[dst] = pay;
  }
}

// --- layer-3 pruning: mark rows read by the accumulators, degree-binned list.
__global__ void mark_rows(const int* __restrict__ users, const int* __restrict__ items,
                          int* __restrict__ mark) {
  int i = blockIdx.x * blockDim.x + threadIdx.x;
  if (i >= kB) return;
  mark[users[i]] = 1;
  mark[kUsers + items[i]] = 1;
}

__global__ void sub_hist(const int* __restrict__ rowptr, const int* __restrict__ mark,
                         int* __restrict__ dh) {
  __shared__ int h[64];
  int t = threadIdx.x;
  if (t < 64) h[t] = 0;
  __syncthreads();
  int i = blockIdx.x * 256 + t;
  if (i < kN && mark[i]) {
    int d = min(rowptr[i + 1] - rowptr[i], 63);
    atomicAdd(&h[d], 1);
  }
  __syncthreads();
  if (t < 64 && h[t]) atomicAdd(&dh[t], h[t]);
}

__global__ void deg_scan(int* __restrict__ dh, int* __restrict__ scnt) {  // 64 thr
  int t = threadIdx.x;
  int v = dh[t];
  int x = v;
  for (int o = 1; o < 64; o <<= 1) {
    int y = __shfl_up(x, o, 64);
    if (t >= o) x += y;
  }
  if (t == 63) *scnt = x;
  dh[t] = x - v;   // exclusive bin base
}

__global__ void sub_place(const int* __restrict__ rowptr, const int* __restrict__ mark,
                          int* __restrict__ dh, int* __restrict__ list) {
  __shared__ int h[64], base[64];
  int t = threadIdx.x;
  if (t < 64) h[t] = 0;
  __syncthreads();
  int i = blockIdx.x * 256 + t;
  int d = 0, lr = 0;
  bool okv = (i < kN) && mark[i];
  if (okv) {
    d = min(rowptr[i + 1] - rowptr[i], 63);
    lr = atomicAdd(&h[d], 1);
  }
  __syncthreads();
  if (t < 64) base[t] = h[t] ? atomicAdd(&dh[t], h[t]) : 0;
  __syncthreads();
  if (okv) list[base[d] + lr] = i;
}

// Union the subset rows' edge endpoints into mark: layer-2 output is only
// consumed at subset rows (acc_add) and at cols of subset rows' edges (spmm
// layer 3) -> spmm layer 2 can skip ~16% of rows.
__global__ void mark_cols(const int* __restrict__ list, const int* __restrict__ cnt,
                          const int* __restrict__ rowptr, const int* __restrict__ edges,
                          int* __restrict__ mark) {
  int p = blockIdx.x * blockDim.x + threadIdx.x;
  if (p >= *cnt) return;
  int r = list[p];
  int s = rowptr[r], e = rowptr[r + 1];
  for (int j = s; j < e; ++j) mark[edges[j] & 0x7FFFF] = 1;
}

// Convert concat(uemb, iemb) to fp8 e4m3, stored = 64*true. One thread per 8
// elems. nt loads: fp32 embeddings never re-read in bulk.
__global__ void to_fp8(const float* __restrict__ ue, const float* __restrict__ ie,
                       unsigned char* __restrict__ xq) {
  int t = blockIdx.x * blockDim.x + threadIdx.x;
  if (t >= kN * kD / 8) return;
  int row = t >> 3;
  int seg = t & 7;
  const float* src = (row < kUsers) ? (ue + (size_t)row * kD + seg * 8)
                                    : (ie + (size_t)(row - kUsers) * kD + seg * 8);
  v4f a = __builtin_nontemporal_load((const v4f*)src);
  v4f b = __builtin_nontemporal_load((const v4f*)src + 1);
  float f[8] = {a.x, a.y, a.z, a.w, b.x, b.y, b.z, b.w};
  unsigned int w0 = 0, w1 = 0;
#pragma unroll
  for (int k = 0; k < 4; ++k) w0 |= (unsigned int)enc(f[k] * 64.f) << (8 * k);
#pragma unroll
  for (int k = 0; k < 4; ++k) w1 |= (unsigned int)enc(f[4 + k] * 64.f) << (8 * k);
  v2i o; o.x = (int)w0; o.y = (int)w1;
  ((v2i*)xq)[t] = o;
}

// Reduction-free spmm, fp8 in / fp8 out (both scaled 64*true). One 8-lane
// group per row; lane l owns dims [8l,8l+8) = one 8-byte gather. Unroll-4
// edge prefetch. MODE 0: all rows. MODE 1: rows with aux[r]!=0. MODE 2: rows
// from aux list (subset). Identity row order for 0/1 (round-2 lesson).
// Round-6 counters: fetch-rate-bound at ~3.67 TB/s, within ~10% of the
// 272 MB / 3.67 TB/s floor -> structure frozen.
template <int MODE>
__global__ __launch_bounds__(256, 8) void spmm(
    const int* __restrict__ rowptr, const int* __restrict__ edges,
    const unsigned char* __restrict__ x, unsigned char* __restrict__ yq,
    const int* __restrict__ aux, const int* __restrict__ cnt) {
  int t = threadIdx.x;
  int l = t & 7;                               // dim octet
  int wid = (blockIdx.x * 256 + t) >> 6;       // global wave id
  int g = (t >> 3) & 7;                        // group (row) within wave
  int p = wid * 8 + g;
  int r = -1;
  bool live = false;
  if (MODE == 2) {
    int n = *cnt;
    if (p < n) { r = aux[p]; live = true; }
  } else {
    if (p < kN) { r = p; live = (MODE == 0) || (aux[r] != 0); }
  }
  int s = 0, e = 0;
  if (live) { s = rowptr[r]; e = rowptr[r + 1]; }
  int mx = e - s;
#pragma unroll
  for (int m = 8; m <= 32; m <<= 1) mx = max(mx, __shfl_xor(mx, m, 64));
  float acc[8];
#pragma unroll
  for (int k = 0; k < 8; ++k) acc[k] = 0.f;
  int last = max(e - 1, 0);
  int j = s;
  int E0 = edges[min(j, last)];
  int E1 = edges[min(j + 1, last)];
  int E2 = edges[min(j + 2, last)];
  int E3 = edges[min(j + 3, last)];
  for (int it = 0; it < mx; it += 4) {
    float v0 = (j     < e) ? vdec(E0) : 0.f;
    float v1 = (j + 1 < e) ? vdec(E1) : 0.f;
    float v2 = (j + 2 < e) ? vdec(E2) : 0.f;
    float v3 = (j + 3 < e) ? vdec(E3) : 0.f;
    v2i h0 = ((const v2i*)(x + (size_t)(E0 & 0x7FFFF) * kD))[l];
    v2i h1 = ((const v2i*)(x + (size_t)(E1 & 0x7FFFF) * kD))[l];
    v2i h2 = ((const v2i*)(x + (size_t)(E2 & 0x7FFFF) * kD))[l];
    v2i h3 = ((const v2i*)(x + (size_t)(E3 & 0x7FFFF) * kD))[l];
    j += 4;
    E0 = edges[min(j, last)];                  // prefetch next quad (clamped)
    E1 = edges[min(j + 1, last)];
    E2 = edges[min(j + 2, last)];
    E3 = edges[min(j + 3, last)];
    float f[8];
    dec8(h0, f);
#pragma unroll
    for (int k = 0; k < 8; ++k) acc[k] = fmaf(v0, f[k], acc[k]);
    dec8(h1, f);
#pragma unroll
    for (int k = 0; k < 8; ++k) acc[k] = fmaf(v1, f[k], acc[k]);
    dec8(h2, f);
#pragma unroll
    for (int k = 0; k < 8; ++k) acc[k] = fmaf(v2, f[k], acc[k]);
    dec8(h3, f);
#pragma unroll
    for (int k = 0; k < 8; ++k) acc[k] = fmaf(v3, f[k], acc[k]);
  }
  if (live) {
    unsigned int w0 = 0, w1 = 0;
#pragma unroll
    for (int k = 0; k < 4; ++k) w0 |= (unsigned int)enc(acc[k]) << (8 * k);
#pragma unroll
    for (int k = 0; k < 4; ++k) w1 |= (unsigned int)enc(acc[4 + k]) << (8 * k);
    v2i o; o.x = (int)w0; o.y = (int)w1;
    ((v2i*)yq)[(size_t)r * 8 + l] = o;
  }
}

// acc = emb_gather + layer1 (fp8 layer output, stored = 64*true -> dec1)
__global__ void acc_add_init(const int* __restrict__ users, const int* __restrict__ items,
                             const float* __restrict__ uemb, const float* __restrict__ iemb,
                             const unsigned char* __restrict__ xq, float* __restrict__ uacc,
                             float* __restrict__ iacc) {
  int tid = blockIdx.x * blockDim.x + threadIdx.x;
  if (tid >= kB * kD) return;
  int b = tid >> 6, d = tid & 63;
  int u = users[b], iw = items[b];
  uacc[tid] = uemb[(size_t)u * kD + d] + dec1(xq[(size_t)u * kD + d]);
  iacc[tid] = iemb[(size_t)iw * kD + d] + dec1(xq[(size_t)(kUsers + iw) * kD + d]);
}

__global__ void acc_add(const int* __restrict__ users, const int* __restrict__ items,
                        const unsigned char* __restrict__ xq, float* __restrict__ uacc,
                        float* __restrict__ iacc) {
  int tid = blockIdx.x * blockDim.x + threadIdx.x;
  if (tid >= kB * kD) return;
  int b = tid >> 6, d = tid & 63;
  uacc[tid] += dec1(xq[(size_t)users[b] * kD + d]);
  iacc[tid] += dec1(xq[(size_t)(kUsers + items[b]) * kD + d]);
}

// layer-3 accumulate + dot + scale, fused
__global__ void acc_add_fin(const int* __restrict__ users, const int* __restrict__ items,
                            const unsigned char* __restrict__ xq, const float* __restrict__ uacc,
                            const float* __restrict__ iacc, float* __restrict__ out) {
  int tid = blockIdx.x * blockDim.x + threadIdx.x;
  if (tid >= kB * kD) return;
  int b = tid >> 6, d = tid & 63;
  float u = uacc[tid] + dec1(xq[(size_t)users[b] * kD + d]);
  float v = iacc[tid] + dec1(xq[(size_t)(kUsers + items[b]) * kD + d]);
  float p = u * v;
  for (int o = 32; o > 0; o >>= 1) p += __shfl_down(p, o, 64);
  if (d == 0) out[b] = p * 0.0625f;
}

}  // namespace

extern "C" void kernel_launch(void* const* d_in, const int* in_sizes, int n_in,
                              void* d_out, int out_size, void* d_ws, size_t ws_size,
                              hipStream_t stream) {
  const int*   users = (const int*)d_in[0];
  const int*   items = (const int*)d_in[1];
  const int*   erow  = (const int*)d_in[2];
  const int*   ecol  = (const int*)d_in[3];
  const float* evals = (const float*)d_in[4];
  const float* uemb  = (const float*)d_in[5];
  const float* iemb  = (const float*)d_in[6];
  float* out = (float*)d_out;

  char* ws = (char*)d_ws;
  size_t off = 0;
  auto take = [&](size_t bytes) -> char* {
    char* p = ws + off;
    off = (off + bytes + 255) & ~(size_t)255;
    return p;
  };
  int*    rowptr   = (int*)take((size_t)(kN + 1) * 4);
  int*    gpos     = (int*)take((kNBKT + 1) * 4);
  int*    partials = (int*)take(256 * 4);
  int*    dh       = (int*)take(256 * 4);    // DEDICATED (round-5 lesson)
  int*    mark     = (int*)take((size_t)kN * 4);
  int*    rowcnt   = (int*)take((size_t)kN * 4);   // row histogram, then cursors
  int*    list     = (int*)take((size_t)kMaxSub * 4);
  int*    scnt     = (int*)take(256);
  int*    edges    = (int*)take((size_t)kNNZ * 4);                   // 20 MB packed
  int*    tmp4     = (int*)take((size_t)kNBKT * kCap * 4);           // 24 MB payload
  unsigned short* tmpr = (unsigned short*)take((size_t)kNBKT * kCap * 2);  // 12 MB rowlocal
  unsigned char* xq0 = (unsigned char*)take((size_t)kN * kD);        // fp8 ping (19.2 MB)
  unsigned char* xq1 = (unsigned char*)take((size_t)kN * kD);        // fp8 pong
  float*  uacc     = (float*)take((size_t)kB * kD * 4);
  float*  iacc     = (float*)take((size_t)kB * kD * 4);
  int*    rowcur   = rowcnt;   // cursors reuse rowcnt (last read: scanR)
  (void)ws_size; (void)in_sizes; (void)n_in; (void)out_size;

  const int nScatBlocks = (kNNZ + kSEPB - 1) / kSEPB;  // 1221
  const int nSpmmBlocks = (kN + 31) / 32;              // 8 rows/wave, 4 waves/block
  const int nSubBlocks  = (kMaxSub + 31) / 32;         // 1024
  const int nRowBlocks  = (kN + 255) / 256;            // 1172

  // --- CSR build: bucket sort w/ fused row histogram, scan, cursor place ---
  zero4<<<nRowBlocks, 256, 0, stream>>>(gpos, mark, rowcnt, dh, scnt);
  bucket_scatter<<<nScatBlocks, 256, 0, stream>>>(erow, ecol, evals, gpos, rowcnt,
                                                  tmp4, tmpr);
  scanR<<<kNBKT, 256, 0, stream>>>(rowcnt, rowptr, partials);
  scan2<<<1, 256, 0, stream>>>(partials);
  scan3<<<(kN + 1 + 255) / 256, 256, 0, stream>>>(rowptr, partials, rowcur);
  place<<<kNBKT * kMC, 256, 0, stream>>>(gpos, tmp4, tmpr, rowcur, edges);

  // --- layer-3 row subset, degree-binned; then union its edge endpoints into
  //     mark for the layer-2 row mask ---
  mark_rows<<<(kB + 255) / 256, 256, 0, stream>>>(users, items, mark);
  sub_hist<<<nRowBlocks, 256, 0, stream>>>(rowptr, mark, dh);
  deg_scan<<<1, 64, 0, stream>>>(dh, scnt);
  sub_place<<<nRowBlocks, 256, 0, stream>>>(rowptr, mark, dh, list);
  mark_cols<<<(kMaxSub + 255) / 256, 256, 0, stream>>>(list, scnt, rowptr, edges, mark);

  // --- fp8 copy of concat embeddings ---
  to_fp8<<<(kN * kD / 8 + 255) / 256, 256, 0, stream>>>(uemb, iemb, xq0);
  // --- 3 propagation layers; fp8 ping-pong; layer 2 masked, layer 3 subset ---
  spmm<0><<<nSpmmBlocks, 256, 0, stream>>>(rowptr, edges, xq0, xq1, nullptr, nullptr);
  acc_add_init<<<(kB * kD) / 256, 256, 0, stream>>>(users, items, uemb, iemb, xq1, uacc, iacc);
  spmm<1><<<nSpmmBlocks, 256, 0, stream>>>(rowptr, edges, xq1, xq0, mark, nullptr);
  acc_add<<<(kB * kD) / 256, 256, 0, stream>>>(users, items, xq0, uacc, iacc);
  spmm<2><<<nSubBlocks, 256, 0, stream>>>(rowptr, edges, xq0, xq1, list, scnt);
  acc_add_fin<<<(kB * kD) / 256, 256, 0, stream>>>(users, items, xq1, uacc, iacc, out);
}

// Round 8
// 519.153 us; speedup vs baseline: 1.8365x; 1.8365x over previous
//
#include <hip/hip_runtime.h>
#include <hip/hip_fp16.h>
#include <hip/hip_fp8.h>

namespace {

constexpr int kUsers = 100000;
constexpr int kItems = 200000;
constexpr int kN     = kUsers + kItems;   // 300000
constexpr int kD     = 64;
constexpr int kNNZ   = 5000000;
constexpr int kB     = 16384;
constexpr int kRowsPerBkt = 2048;                       // rows per coarse bucket
constexpr int kNBKT  = (kN + kRowsPerBkt - 1) / kRowsPerBkt;  // 147
constexpr int kSEPB  = 4096;                            // edges per bucket_scatter block
constexpr int kCap   = 40960;                           // slots/bucket (mean 34133, sd 185)
constexpr int kMaxSub = 2 * kB;                         // upper bound on marked rows

typedef int   v2i __attribute__((ext_vector_type(2)));
typedef float v4f __attribute__((ext_vector_type(4)));

// --- fp8 e4m3 storage: buffers hold 64*true_value. Native v_cvt_pk_f32_fp8
// decode (round-6: VALUBusy 71->46%, spmm -15%). Bit-trick fallback yields
// stored/256, patched by kValScale on the edge weight. Builtins return PLAIN
// float vectors -> index with [].
#if defined(__has_builtin)
#if __has_builtin(__builtin_amdgcn_cvt_pk_f32_fp8) && __has_builtin(__builtin_amdgcn_cvt_f32_fp8)
#define NATIVE_FP8 1
#endif
#endif
#ifndef NATIVE_FP8
#define NATIVE_FP8 0
#endif

constexpr float kValScale = NATIVE_FP8 ? 1.0f : 256.0f;

__device__ inline void dec8(v2i h, float* f) {
#if NATIVE_FP8
  auto a0 = __builtin_amdgcn_cvt_pk_f32_fp8(h.x, false);
  auto a1 = __builtin_amdgcn_cvt_pk_f32_fp8(h.x, true);
  auto a2 = __builtin_amdgcn_cvt_pk_f32_fp8(h.y, false);
  auto a3 = __builtin_amdgcn_cvt_pk_f32_fp8(h.y, true);
  f[0] = a0[0]; f[1] = a0[1]; f[2] = a1[0]; f[3] = a1[1];
  f[4] = a2[0]; f[5] = a2[1]; f[6] = a3[0]; f[7] = a3[1];
#else
  unsigned int ws[2] = {(unsigned int)h.x, (unsigned int)h.y};
#pragma unroll
  for (int q = 0; q < 2; ++q) {
    unsigned int w = ws[q];
    unsigned int a = ((w & 0x007f007fu) << 7) | ((w & 0x00800080u) << 8);
    unsigned int b = (((w >> 8) & 0x007f007fu) << 7) | (((w >> 8) & 0x00800080u) << 8);
    float2 e = __half22float2(*reinterpret_cast<const __half2*>(&a));
    float2 o = __half22float2(*reinterpret_cast<const __half2*>(&b));
    f[4 * q + 0] = e.x; f[4 * q + 1] = o.x; f[4 * q + 2] = e.y; f[4 * q + 3] = o.y;
  }
#endif
}

__device__ inline float dec1(unsigned char b) {  // stored(=64*true) -> true
#if NATIVE_FP8
  return __builtin_amdgcn_cvt_f32_fp8((int)b, 0) * 0.015625f;
#else
  unsigned int hb = ((b & 0x7fu) << 7) | ((b & 0x80u) << 8);
  return __half2float(__ushort_as_half((unsigned short)hb)) * 4.0f;
#endif
}

__device__ inline unsigned char enc(float f) { __hip_fp8_e4m3 q(f); return q.__x; }

// packed edge: bits[18:0] = col, bits[31:19] = val13 (fp16 bits rounded to
// 5-exp + 8-mantissa; vals >= 0 so no sign bit). rel err 2^-9.
__device__ inline float vdec(int w) {
  return __half2float(__ushort_as_half((unsigned short)((w >> 17) & 0x7FFC))) * kValScale;
}

__global__ void zero3(int* __restrict__ gpos, int* __restrict__ mark,
                      int* __restrict__ dh, int* __restrict__ scnt) {
  int i = blockIdx.x * blockDim.x + threadIdx.x;
  if (i < kN) mark[i] = 0;
  if (i < kNBKT + 1) gpos[i] = 0;
  if (i < 64) dh[i] = 0;   // dh DEDICATED (round-5: aliasing partials -> OOB)
  if (i == 0) scnt[0] = 0;
}

// Counting-sort partition of 4096 edges into 147 coarse buckets; per-wave LDS
// histograms (4x147) cut same-address atomic serialization 4x. LDS staging so
// tmp writes go out in coalesced bucket-run bursts. NO per-row global atomics
// (round-7 lesson: 5M device-scope atomics = memory-side RMW = 302 MB MALL
// write + 350 us; counting stays in LDS / per-bucket kernels). tmp split:
// 4 B payload + 2 B rowlocal (6 B/edge).
__global__ void bucket_scatter(const int* __restrict__ row, const int* __restrict__ col,
                               const float* __restrict__ val, int* __restrict__ gpos,
                               int* __restrict__ tmp4, unsigned short* __restrict__ tmpr) {
  __shared__ int hcnt[4][kNBKT];   // per-wave counts -> wave-exclusive offsets
  __shared__ int lofs[kNBKT];
  __shared__ int hbase[kNBKT];
  __shared__ int lds[256];
  __shared__ int sp[kSEPB];              // payload stage
  __shared__ unsigned short sr[kSEPB];   // rowlocal stage
  __shared__ unsigned short sb[kSEPB];   // bucket stage
  int t = threadIdx.x;
  int wv = t >> 6;
  long base = (long)blockIdx.x * kSEPB;
  int valid = (int)min((long)kSEPB, (long)kNNZ - base);
  for (int i = t; i < kNBKT; i += 256) {
    hcnt[0][i] = 0; hcnt[1][i] = 0; hcnt[2][i] = 0; hcnt[3][i] = 0;
  }
  __syncthreads();
  int py[16], bk[16], rl[16], rk[16];
  bool ok[16];
#pragma unroll
  for (int j = 0; j < 16; ++j) {
    long i = base + j * 256 + t;
    ok[j] = (i < kNNZ);
    if (ok[j]) {
      int r = __builtin_nontemporal_load(row + i);
      int c = __builtin_nontemporal_load(col + i);
      float v = __builtin_nontemporal_load(val + i);
      bk[j] = r >> 11;
      rl[j] = r & 2047;
      unsigned short hb = __half_as_ushort(__float2half_rn(v));
      int v13 = ((int)hb + 2) >> 2;              // round to exp5+man8
      py[j] = c | (v13 << 19);
      rk[j] = atomicAdd(&hcnt[wv][bk[j]], 1);
    }
  }
  __syncthreads();
  int own = 0;
  if (t < kNBKT) {
    int c0 = hcnt[0][t], c1 = hcnt[1][t], c2 = hcnt[2][t], c3 = hcnt[3][t];
    hcnt[0][t] = 0; hcnt[1][t] = c0; hcnt[2][t] = c0 + c1; hcnt[3][t] = c0 + c1 + c2;
    own = c0 + c1 + c2 + c3;
  }
  lds[t] = own;
  __syncthreads();
  for (int o = 1; o < 256; o <<= 1) {
    int x = (t >= o) ? lds[t - o] : 0;
    __syncthreads();
    if (t >= o) lds[t] += x;
    __syncthreads();
  }
  if (t < kNBKT) {
    lofs[t] = lds[t] - own;
    hbase[t] = t * kCap + atomicAdd(&gpos[t], own);
  }
  __syncthreads();
#pragma unroll
  for (int j = 0; j < 16; ++j) {
    if (ok[j]) {
      int pos = lofs[bk[j]] + hcnt[wv][bk[j]] + rk[j];
      sp[pos] = py[j];
      sr[pos] = (unsigned short)rl[j];
      sb[pos] = (unsigned short)bk[j];
    }
  }
  __syncthreads();
#pragma unroll
  for (int j = 0; j < 16; ++j) {
    int pos = t + j * 256;
    if (pos < valid) {
      int b = sb[pos];
      int w = hbase[b] + (pos - lofs[b]);
      tmp4[w] = sp[pos];
      tmpr[w] = sr[pos];
    }
  }
}

// Grid = kNBKT, one block per bucket: LDS histogram over the bucket's rowlocal
// stream (2 B/edge, 10 MB total) + in-block scan -> bucket-local rowptr +
// partial. Fuses round-6's chunk_hist + scanA; ctab deleted.
__global__ void hist_scan(const int* __restrict__ gpos,
                          const unsigned short* __restrict__ tmpr,
                          int* __restrict__ rowptr, int* __restrict__ partials) {
  __shared__ int h[kRowsPerBkt];
  __shared__ int lsum[256];
  int b = blockIdx.x, t = threadIdx.x;
  for (int i = t; i < kRowsPerBkt; i += 256) h[i] = 0;
  __syncthreads();
  int s = b * kCap;
  int e = s + gpos[b];
  for (int j = s + t; j < e; j += 256) atomicAdd(&h[tmpr[j]], 1);
  __syncthreads();
  int cnt[8], pref[8];
  int acc = 0;
#pragma unroll
  for (int k = 0; k < 8; ++k) {
    cnt[k] = h[t * 8 + k];
    pref[k] = acc;
    acc += cnt[k];
  }
  lsum[t] = acc;
  __syncthreads();
  for (int o = 1; o < 256; o <<= 1) {
    int v = (t >= o) ? lsum[t - o] : 0;
    __syncthreads();
    if (t >= o) lsum[t] += v;
    __syncthreads();
  }
  int ex = (t == 0) ? 0 : lsum[t - 1];
#pragma unroll
  for (int k = 0; k < 8; ++k) {
    int r = b * kRowsPerBkt + t * 8 + k;
    if (r < kN) rowptr[r] = ex + pref[k];
  }
  if (t == 255) partials[b] = lsum[255];
}

__global__ void scan2(int* __restrict__ partials) {
  __shared__ int lds[256];
  int t = threadIdx.x;
  lds[t] = (t < kNBKT) ? partials[t] : 0;
  __syncthreads();
  for (int o = 1; o < 256; o <<= 1) {
    int v = (t >= o) ? lds[t - o] : 0;
    __syncthreads();
    if (t >= o) lds[t] += v;
    __syncthreads();
  }
  int ex = (t == 0) ? 0 : lds[t - 1];
  if (t < kNBKT) partials[t] = ex;
}

__global__ void scan3(int* __restrict__ rowptr, const int* __restrict__ partials) {
  int i = blockIdx.x * blockDim.x + threadIdx.x;
  if (i < kN) rowptr[i] += partials[i >> 11];
  else if (i == kN) rowptr[kN] = kNNZ;
}

// Grid = kNBKT, ONE block per bucket (1024 threads for latency hiding at
// 147-block occupancy): LDS rank + scattered 4 B stores confined to the
// bucket's ~136 KB window, all from ONE XCD -> L2 lines fill completely
// before write-back (round-7 lesson: multi-XCD partial lines = 15x write
// amplification). No ctab/coff needed: rank starts at 0 for the whole bucket.
__global__ __launch_bounds__(1024) void place(
    const int* __restrict__ gpos, const int* __restrict__ tmp4,
    const unsigned short* __restrict__ tmpr, const int* __restrict__ rowptr,
    int* __restrict__ edges) {
  __shared__ int rank[kRowsPerBkt];
  int b = blockIdx.x, t = threadIdx.x;
  for (int i = t; i < kRowsPerBkt; i += 1024) rank[i] = 0;
  __syncthreads();
  int s = b * kCap;
  int e = s + gpos[b];
  const int* rp = rowptr + b * kRowsPerBkt;
  for (int j = s + t; j < e; j += 1024) {
    int pay = tmp4[j];
    int rl = tmpr[j];
    int k = atomicAdd(&rank[rl], 1);
    edges[rp[rl] + k] = pay;
  }
}

// --- layer-3 pruning: mark rows read by the accumulators, degree-binned list.
__global__ void mark_rows(const int* __restrict__ users, const int* __restrict__ items,
                          int* __restrict__ mark) {
  int i = blockIdx.x * blockDim.x + threadIdx.x;
  if (i >= kB) return;
  mark[users[i]] = 1;
  mark[kUsers + items[i]] = 1;
}

__global__ void sub_hist(const int* __restrict__ rowptr, const int* __restrict__ mark,
                         int* __restrict__ dh) {
  __shared__ int h[64];
  int t = threadIdx.x;
  if (t < 64) h[t] = 0;
  __syncthreads();
  int i = blockIdx.x * 256 + t;
  if (i < kN && mark[i]) {
    int d = min(rowptr[i + 1] - rowptr[i], 63);
    atomicAdd(&h[d], 1);
  }
  __syncthreads();
  if (t < 64 && h[t]) atomicAdd(&dh[t], h[t]);
}

__global__ void deg_scan(int* __restrict__ dh, int* __restrict__ scnt) {  // 64 thr
  int t = threadIdx.x;
  int v = dh[t];
  int x = v;
  for (int o = 1; o < 64; o <<= 1) {
    int y = __shfl_up(x, o, 64);
    if (t >= o) x += y;
  }
  if (t == 63) *scnt = x;
  dh[t] = x - v;   // exclusive bin base
}

__global__ void sub_place(const int* __restrict__ rowptr, const int* __restrict__ mark,
                          int* __restrict__ dh, int* __restrict__ list) {
  __shared__ int h[64], base[64];
  int t = threadIdx.x;
  if (t < 64) h[t] = 0;
  __syncthreads();
  int i = blockIdx.x * 256 + t;
  int d = 0, lr = 0;
  bool okv = (i < kN) && mark[i];
  if (okv) {
    d = min(rowptr[i + 1] - rowptr[i], 63);
    lr = atomicAdd(&h[d], 1);
  }
  __syncthreads();
  if (t < 64) base[t] = h[t] ? atomicAdd(&dh[t], h[t]) : 0;
  __syncthreads();
  if (okv) list[base[d] + lr] = i;
}

// Union the subset rows' edge endpoints into mark: layer-2 output is only
// consumed at subset rows (acc_add) and at cols of subset rows' edges (spmm
// layer 3) -> spmm layer 2 can skip ~16% of rows.
__global__ void mark_cols(const int* __restrict__ list, const int* __restrict__ cnt,
                          const int* __restrict__ rowptr, const int* __restrict__ edges,
                          int* __restrict__ mark) {
  int p = blockIdx.x * blockDim.x + threadIdx.x;
  if (p >= *cnt) return;
  int r = list[p];
  int s = rowptr[r], e = rowptr[r + 1];
  for (int j = s; j < e; ++j) mark[edges[j] & 0x7FFFF] = 1;
}

// Convert concat(uemb, iemb) to fp8 e4m3, stored = 64*true. One thread per 8
// elems. nt loads: fp32 embeddings never re-read in bulk.
__global__ void to_fp8(const float* __restrict__ ue, const float* __restrict__ ie,
                       unsigned char* __restrict__ xq) {
  int t = blockIdx.x * blockDim.x + threadIdx.x;
  if (t >= kN * kD / 8) return;
  int row = t >> 3;
  int seg = t & 7;
  const float* src = (row < kUsers) ? (ue + (size_t)row * kD + seg * 8)
                                    : (ie + (size_t)(row - kUsers) * kD + seg * 8);
  v4f a = __builtin_nontemporal_load((const v4f*)src);
  v4f b = __builtin_nontemporal_load((const v4f*)src + 1);
  float f[8] = {a.x, a.y, a.z, a.w, b.x, b.y, b.z, b.w};
  unsigned int w0 = 0, w1 = 0;
#pragma unroll
  for (int k = 0; k < 4; ++k) w0 |= (unsigned int)enc(f[k] * 64.f) << (8 * k);
#pragma unroll
  for (int k = 0; k < 4; ++k) w1 |= (unsigned int)enc(f[4 + k] * 64.f) << (8 * k);
  v2i o; o.x = (int)w0; o.y = (int)w1;
  ((v2i*)xq)[t] = o;
}

// Reduction-free spmm, fp8 in / fp8 out (both scaled 64*true). One 8-lane
// group per row; lane l owns dims [8l,8l+8) = one 8-byte gather. Unroll-4
// edge prefetch. MODE 0: all rows. MODE 1: rows with aux[r]!=0. MODE 2: rows
// from aux list (subset). Identity row order for 0/1 (round-2 lesson).
// Round-6 counters: fetch-rate-bound ~3.67 TB/s, within ~10% of the
// 272 MB floor -> structure frozen.
template <int MODE>
__global__ __launch_bounds__(256, 8) void spmm(
    const int* __restrict__ rowptr, const int* __restrict__ edges,
    const unsigned char* __restrict__ x, unsigned char* __restrict__ yq,
    const int* __restrict__ aux, const int* __restrict__ cnt) {
  int t = threadIdx.x;
  int l = t & 7;                               // dim octet
  int wid = (blockIdx.x * 256 + t) >> 6;       // global wave id
  int g = (t >> 3) & 7;                        // group (row) within wave
  int p = wid * 8 + g;
  int r = -1;
  bool live = false;
  if (MODE == 2) {
    int n = *cnt;
    if (p < n) { r = aux[p]; live = true; }
  } else {
    if (p < kN) { r = p; live = (MODE == 0) || (aux[r] != 0); }
  }
  int s = 0, e = 0;
  if (live) { s = rowptr[r]; e = rowptr[r + 1]; }
  int mx = e - s;
#pragma unroll
  for (int m = 8; m <= 32; m <<= 1) mx = max(mx, __shfl_xor(mx, m, 64));
  float acc[8];
#pragma unroll
  for (int k = 0; k < 8; ++k) acc[k] = 0.f;
  int last = max(e - 1, 0);
  int j = s;
  int E0 = edges[min(j, last)];
  int E1 = edges[min(j + 1, last)];
  int E2 = edges[min(j + 2, last)];
  int E3 = edges[min(j + 3, last)];
  for (int it = 0; it < mx; it += 4) {
    float v0 = (j     < e) ? vdec(E0) : 0.f;
    float v1 = (j + 1 < e) ? vdec(E1) : 0.f;
    float v2 = (j + 2 < e) ? vdec(E2) : 0.f;
    float v3 = (j + 3 < e) ? vdec(E3) : 0.f;
    v2i h0 = ((const v2i*)(x + (size_t)(E0 & 0x7FFFF) * kD))[l];
    v2i h1 = ((const v2i*)(x + (size_t)(E1 & 0x7FFFF) * kD))[l];
    v2i h2 = ((const v2i*)(x + (size_t)(E2 & 0x7FFFF) * kD))[l];
    v2i h3 = ((const v2i*)(x + (size_t)(E3 & 0x7FFFF) * kD))[l];
    j += 4;
    E0 = edges[min(j, last)];                  // prefetch next quad (clamped)
    E1 = edges[min(j + 1, last)];
    E2 = edges[min(j + 2, last)];
    E3 = edges[min(j + 3, last)];
    float f[8];
    dec8(h0, f);
#pragma unroll
    for (int k = 0; k < 8; ++k) acc[k] = fmaf(v0, f[k], acc[k]);
    dec8(h1, f);
#pragma unroll
    for (int k = 0; k < 8; ++k) acc[k] = fmaf(v1, f[k], acc[k]);
    dec8(h2, f);
#pragma unroll
    for (int k = 0; k < 8; ++k) acc[k] = fmaf(v2, f[k], acc[k]);
    dec8(h3, f);
#pragma unroll
    for (int k = 0; k < 8; ++k) acc[k] = fmaf(v3, f[k], acc[k]);
  }
  if (live) {
    unsigned int w0 = 0, w1 = 0;
#pragma unroll
    for (int k = 0; k < 4; ++k) w0 |= (unsigned int)enc(acc[k]) << (8 * k);
#pragma unroll
    for (int k = 0; k < 4; ++k) w1 |= (unsigned int)enc(acc[4 + k]) << (8 * k);
    v2i o; o.x = (int)w0; o.y = (int)w1;
    ((v2i*)yq)[(size_t)r * 8 + l] = o;
  }
}

// acc = emb_gather + layer1 (fp8 layer output, stored = 64*true -> dec1)
__global__ void acc_add_init(const int* __restrict__ users, const int* __restrict__ items,
                             const float* __restrict__ uemb, const float* __restrict__ iemb,
                             const unsigned char* __restrict__ xq, float* __restrict__ uacc,
                             float* __restrict__ iacc) {
  int tid = blockIdx.x * blockDim.x + threadIdx.x;
  if (tid >= kB * kD) return;
  int b = tid >> 6, d = tid & 63;
  int u = users[b], iw = items[b];
  uacc[tid] = uemb[(size_t)u * kD + d] + dec1(xq[(size_t)u * kD + d]);
  iacc[tid] = iemb[(size_t)iw * kD + d] + dec1(xq[(size_t)(kUsers + iw) * kD + d]);
}

__global__ void acc_add(const int* __restrict__ users, const int* __restrict__ items,
                        const unsigned char* __restrict__ xq, float* __restrict__ uacc,
                        float* __restrict__ iacc) {
  int tid = blockIdx.x * blockDim.x + threadIdx.x;
  if (tid >= kB * kD) return;
  int b = tid >> 6, d = tid & 63;
  uacc[tid] += dec1(xq[(size_t)users[b] * kD + d]);
  iacc[tid] += dec1(xq[(size_t)(kUsers + items[b]) * kD + d]);
}

// layer-3 accumulate + dot + scale, fused
__global__ void acc_add_fin(const int* __restrict__ users, const int* __restrict__ items,
                            const unsigned char* __restrict__ xq, const float* __restrict__ uacc,
                            const float* __restrict__ iacc, float* __restrict__ out) {
  int tid = blockIdx.x * blockDim.x + threadIdx.x;
  if (tid >= kB * kD) return;
  int b = tid >> 6, d = tid & 63;
  float u = uacc[tid] + dec1(xq[(size_t)users[b] * kD + d]);
  float v = iacc[tid] + dec1(xq[(size_t)(kUsers + items[b]) * kD + d]);
  float p = u * v;
  for (int o = 32; o > 0; o >>= 1) p += __shfl_down(p, o, 64);
  if (d == 0) out[b] = p * 0.0625f;
}

}  // namespace

extern "C" void kernel_launch(void* const* d_in, const int* in_sizes, int n_in,
                              void* d_out, int out_size, void* d_ws, size_t ws_size,
                              hipStream_t stream) {
  const int*   users = (const int*)d_in[0];
  const int*   items = (const int*)d_in[1];
  const int*   erow  = (const int*)d_in[2];
  const int*   ecol  = (const int*)d_in[3];
  const float* evals = (const float*)d_in[4];
  const float* uemb  = (const float*)d_in[5];
  const float* iemb  = (const float*)d_in[6];
  float* out = (float*)d_out;

  char* ws = (char*)d_ws;
  size_t off = 0;
  auto take = [&](size_t bytes) -> char* {
    char* p = ws + off;
    off = (off + bytes + 255) & ~(size_t)255;
    return p;
  };
  int*    rowptr   = (int*)take((size_t)(kN + 1) * 4);
  int*    gpos     = (int*)take((kNBKT + 1) * 4);
  int*    partials = (int*)take(256 * 4);
  int*    dh       = (int*)take(256 * 4);    // DEDICATED (round-5 lesson)
  int*    mark     = (int*)take((size_t)kN * 4);
  int*    list     = (int*)take((size_t)kMaxSub * 4);
  int*    scnt     = (int*)take(256);
  int*    edges    = (int*)take((size_t)kNNZ * 4);                   // 20 MB packed
  int*    tmp4     = (int*)take((size_t)kNBKT * kCap * 4);           // 24 MB payload
  unsigned short* tmpr = (unsigned short*)take((size_t)kNBKT * kCap * 2);  // 12 MB rowlocal
  unsigned char* xq0 = (unsigned char*)take((size_t)kN * kD);        // fp8 ping (19.2 MB)
  unsigned char* xq1 = (unsigned char*)take((size_t)kN * kD);        // fp8 pong
  float*  uacc     = (float*)take((size_t)kB * kD * 4);
  float*  iacc     = (float*)take((size_t)kB * kD * 4);
  (void)ws_size; (void)in_sizes; (void)n_in; (void)out_size;

  const int nScatBlocks = (kNNZ + kSEPB - 1) / kSEPB;  // 1221
  const int nSpmmBlocks = (kN + 31) / 32;              // 8 rows/wave, 4 waves/block
  const int nSubBlocks  = (kMaxSub + 31) / 32;         // 1024
  const int nRowBlocks  = (kN + 255) / 256;            // 1172

  // --- CSR build: bucket sort; per-bucket hist+scan; per-bucket place ---
  zero3<<<nRowBlocks, 256, 0, stream>>>(gpos, mark, dh, scnt);
  bucket_scatter<<<nScatBlocks, 256, 0, stream>>>(erow, ecol, evals, gpos, tmp4, tmpr);
  hist_scan<<<kNBKT, 256, 0, stream>>>(gpos, tmpr, rowptr, partials);
  scan2<<<1, 256, 0, stream>>>(partials);
  scan3<<<(kN + 1 + 255) / 256, 256, 0, stream>>>(rowptr, partials);
  place<<<kNBKT, 1024, 0, stream>>>(gpos, tmp4, tmpr, rowptr, edges);

  // --- layer-3 row subset, degree-binned; then union its edge endpoints into
  //     mark for the layer-2 row mask ---
  mark_rows<<<(kB + 255) / 256, 256, 0, stream>>>(users, items, mark);
  sub_hist<<<nRowBlocks, 256, 0, stream>>>(rowptr, mark, dh);
  deg_scan<<<1, 64, 0, stream>>>(dh, scnt);
  sub_place<<<nRowBlocks, 256, 0, stream>>>(rowptr, mark, dh, list);
  mark_cols<<<(kMaxSub + 255) / 256, 256, 0, stream>>>(list, scnt, rowptr, edges, mark);

  // --- fp8 copy of concat embeddings ---
  to_fp8<<<(kN * kD / 8 + 255) / 256, 256, 0, stream>>>(uemb, iemb, xq0);
  // --- 3 propagation layers; fp8 ping-pong; layer 2 masked, layer 3 subset ---
  spmm<0><<<nSpmmBlocks, 256, 0, stream>>>(rowptr, edges, xq0, xq1, nullptr, nullptr);
  acc_add_init<<<(kB * kD) / 256, 256, 0, stream>>>(users, items, uemb, iemb, xq1, uacc, iacc);
  spmm<1><<<nSpmmBlocks, 256, 0, stream>>>(rowptr, edges, xq1, xq0, mark, nullptr);
  acc_add<<<(kB * kD) / 256, 256, 0, stream>>>(users, items, xq0, uacc, iacc);
  spmm<2><<<nSubBlocks, 256, 0, stream>>>(rowptr, edges, xq0, xq1, list, scnt);
  acc_add_fin<<<(kB * kD) / 256, 256, 0, stream>>>(users, items, xq1, uacc, iacc, out);
}

// Round 9
// 483.020 us; speedup vs baseline: 1.9738x; 1.0748x over previous
//
#include <hip/hip_runtime.h>
#include <hip/hip_fp16.h>
#include <hip/hip_fp8.h>

namespace {

constexpr int kUsers = 100000;
constexpr int kItems = 200000;
constexpr int kN     = kUsers + kItems;   // 300000
constexpr int kD     = 64;
constexpr int kNNZ   = 5000000;
constexpr int kB     = 16384;
constexpr int kRowsPerBkt = 2048;                       // rows per coarse bucket
constexpr int kNBKT  = (kN + kRowsPerBkt - 1) / kRowsPerBkt;  // 147
constexpr int kSEPB  = 4096;                            // edges per bucket_scatter block
constexpr int kCap   = 40960;                           // slots/bucket (mean 34133, sd 185)
constexpr int kMaxSub = 2 * kB;                         // upper bound on marked rows

typedef int   v2i __attribute__((ext_vector_type(2)));
typedef float v4f __attribute__((ext_vector_type(4)));

// --- fp8 e4m3 storage: buffers hold 64*true_value. Native v_cvt_pk_f32_fp8
// decode (round-6: VALUBusy 71->46%, spmm -15%). Bit-trick fallback yields
// stored/256, patched by kValScale on the edge weight. Builtins return PLAIN
// float vectors -> index with [].
#if defined(__has_builtin)
#if __has_builtin(__builtin_amdgcn_cvt_pk_f32_fp8) && __has_builtin(__builtin_amdgcn_cvt_f32_fp8)
#define NATIVE_FP8 1
#endif
#endif
#ifndef NATIVE_FP8
#define NATIVE_FP8 0
#endif

constexpr float kValScale = NATIVE_FP8 ? 1.0f : 256.0f;

__device__ inline void dec8(v2i h, float* f) {
#if NATIVE_FP8
  auto a0 = __builtin_amdgcn_cvt_pk_f32_fp8(h.x, false);
  auto a1 = __builtin_amdgcn_cvt_pk_f32_fp8(h.x, true);
  auto a2 = __builtin_amdgcn_cvt_pk_f32_fp8(h.y, false);
  auto a3 = __builtin_amdgcn_cvt_pk_f32_fp8(h.y, true);
  f[0] = a0[0]; f[1] = a0[1]; f[2] = a1[0]; f[3] = a1[1];
  f[4] = a2[0]; f[5] = a2[1]; f[6] = a3[0]; f[7] = a3[1];
#else
  unsigned int ws[2] = {(unsigned int)h.x, (unsigned int)h.y};
#pragma unroll
  for (int q = 0; q < 2; ++q) {
    unsigned int w = ws[q];
    unsigned int a = ((w & 0x007f007fu) << 7) | ((w & 0x00800080u) << 8);
    unsigned int b = (((w >> 8) & 0x007f007fu) << 7) | (((w >> 8) & 0x00800080u) << 8);
    float2 e = __half22float2(*reinterpret_cast<const __half2*>(&a));
    float2 o = __half22float2(*reinterpret_cast<const __half2*>(&b));
    f[4 * q + 0] = e.x; f[4 * q + 1] = o.x; f[4 * q + 2] = e.y; f[4 * q + 3] = o.y;
  }
#endif
}

__device__ inline float dec1(unsigned char b) {  // stored(=64*true) -> true
#if NATIVE_FP8
  return __builtin_amdgcn_cvt_f32_fp8((int)b, 0) * 0.015625f;
#else
  unsigned int hb = ((b & 0x7fu) << 7) | ((b & 0x80u) << 8);
  return __half2float(__ushort_as_half((unsigned short)hb)) * 4.0f;
#endif
}

__device__ inline unsigned char enc(float f) { __hip_fp8_e4m3 q(f); return q.__x; }

// packed edge: bits[18:0] = col, bits[31:19] = val13 (fp16 bits rounded to
// 5-exp + 8-mantissa; vals >= 0 so no sign bit). rel err 2^-9.
__device__ inline float vdec(int w) {
  return __half2float(__ushort_as_half((unsigned short)((w >> 17) & 0x7FFC))) * kValScale;
}

__global__ void zero3(int* __restrict__ gpos, int* __restrict__ mark,
                      int* __restrict__ dh, int* __restrict__ scnt) {
  int i = blockIdx.x * blockDim.x + threadIdx.x;
  if (i < kN) mark[i] = 0;
  if (i < kNBKT + 1) gpos[i] = 0;
  if (i < 64) dh[i] = 0;   // dh DEDICATED (round-5: aliasing partials -> OOB)
  if (i == 0) scnt[0] = 0;
}

// Counting-sort partition of 4096 edges into 147 coarse buckets; per-wave LDS
// histograms (4x147) cut same-address atomic serialization 4x. LDS staging so
// tmp writes go out in coalesced bucket-run bursts. NO per-row global atomics
// (round-7 lesson: 5M device-scope atomics = memory-side RMW = 302 MB MALL
// write + 350 us; counting stays in LDS / per-bucket kernels). tmp split:
// 4 B payload + 2 B rowlocal (6 B/edge).
__global__ void bucket_scatter(const int* __restrict__ row, const int* __restrict__ col,
                               const float* __restrict__ val, int* __restrict__ gpos,
                               int* __restrict__ tmp4, unsigned short* __restrict__ tmpr) {
  __shared__ int hcnt[4][kNBKT];   // per-wave counts -> wave-exclusive offsets
  __shared__ int lofs[kNBKT];
  __shared__ int hbase[kNBKT];
  __shared__ int lds[256];
  __shared__ int sp[kSEPB];              // payload stage
  __shared__ unsigned short sr[kSEPB];   // rowlocal stage
  __shared__ unsigned short sb[kSEPB];   // bucket stage
  int t = threadIdx.x;
  int wv = t >> 6;
  long base = (long)blockIdx.x * kSEPB;
  int valid = (int)min((long)kSEPB, (long)kNNZ - base);
  for (int i = t; i < kNBKT; i += 256) {
    hcnt[0][i] = 0; hcnt[1][i] = 0; hcnt[2][i] = 0; hcnt[3][i] = 0;
  }
  __syncthreads();
  int py[16], bk[16], rl[16], rk[16];
  bool ok[16];
#pragma unroll
  for (int j = 0; j < 16; ++j) {
    long i = base + j * 256 + t;
    ok[j] = (i < kNNZ);
    if (ok[j]) {
      int r = __builtin_nontemporal_load(row + i);
      int c = __builtin_nontemporal_load(col + i);
      float v = __builtin_nontemporal_load(val + i);
      bk[j] = r >> 11;
      rl[j] = r & 2047;
      unsigned short hb = __half_as_ushort(__float2half_rn(v));
      int v13 = ((int)hb + 2) >> 2;              // round to exp5+man8
      py[j] = c | (v13 << 19);
      rk[j] = atomicAdd(&hcnt[wv][bk[j]], 1);
    }
  }
  __syncthreads();
  int own = 0;
  if (t < kNBKT) {
    int c0 = hcnt[0][t], c1 = hcnt[1][t], c2 = hcnt[2][t], c3 = hcnt[3][t];
    hcnt[0][t] = 0; hcnt[1][t] = c0; hcnt[2][t] = c0 + c1; hcnt[3][t] = c0 + c1 + c2;
    own = c0 + c1 + c2 + c3;
  }
  lds[t] = own;
  __syncthreads();
  for (int o = 1; o < 256; o <<= 1) {
    int x = (t >= o) ? lds[t - o] : 0;
    __syncthreads();
    if (t >= o) lds[t] += x;
    __syncthreads();
  }
  if (t < kNBKT) {
    lofs[t] = lds[t] - own;
    hbase[t] = t * kCap + atomicAdd(&gpos[t], own);
  }
  __syncthreads();
#pragma unroll
  for (int j = 0; j < 16; ++j) {
    if (ok[j]) {
      int pos = lofs[bk[j]] + hcnt[wv][bk[j]] + rk[j];
      sp[pos] = py[j];
      sr[pos] = (unsigned short)rl[j];
      sb[pos] = (unsigned short)bk[j];
    }
  }
  __syncthreads();
#pragma unroll
  for (int j = 0; j < 16; ++j) {
    int pos = t + j * 256;
    if (pos < valid) {
      int b = sb[pos];
      int w = hbase[b] + (pos - lofs[b]);
      tmp4[w] = sp[pos];
      tmpr[w] = sr[pos];
    }
  }
}

// Grid = kNBKT, ONE 1024-thread block per bucket. Fuses round-8's
// hist_scan + scan2 + scan3 + place into one kernel (-3 launches, -2 pure-
// latency single-block dispatches): the bucket-level prefix is just a scan of
// gpos (final after bucket_scatter), so every block derives its global base
// in-block. Pass 1: LDS row histogram from tmpr. Scan: 2048 rows -> FINAL
// global rowptr written directly; hist becomes global write cursors. Pass 2:
// re-read tmp4/tmpr, place via LDS cursor atomics. All stores to the bucket's
// ~136 KB edges window come from ONE XCD (round-7 lesson: multi-XCD partial
// lines = 15x write amplification; round-8 verified the fix).
__global__ __launch_bounds__(1024) void build_csr(
    const int* __restrict__ gpos, const int* __restrict__ tmp4,
    const unsigned short* __restrict__ tmpr, int* __restrict__ rowptr,
    int* __restrict__ edges) {
  __shared__ int h[kRowsPerBkt];     // hist -> global cursors
  __shared__ int lsum[256];
  __shared__ int gscan[256];
  int b = blockIdx.x, t = threadIdx.x;
  // --- bucket base: in-block inclusive scan of gpos[0..kNBKT) (147 values) ---
  if (t < 256) gscan[t] = (t < kNBKT) ? gpos[t] : 0;
  for (int i = t; i < kRowsPerBkt; i += 1024) h[i] = 0;
  __syncthreads();
  for (int o = 1; o < 256; o <<= 1) {
    int v = 0;
    if (t < 256 && t >= o) v = gscan[t - o];
    __syncthreads();
    if (t < 256 && t >= o) gscan[t] += v;
    __syncthreads();
  }
  int bucket_base = (b == 0) ? 0 : gscan[b - 1];
  int s = b * kCap;
  int e = s + gpos[b];
  // --- pass 1: row histogram over the bucket's rowlocal stream (2 B/edge) ---
  for (int j = s + t; j < e; j += 1024) atomicAdd(&h[tmpr[j]], 1);
  __syncthreads();
  // --- scan 2048 rows (256 threads x 8), write FINAL rowptr, make cursors ---
  int cnt[8], pref[8];
  if (t < 256) {
    int acc = 0;
#pragma unroll
    for (int k = 0; k < 8; ++k) {
      cnt[k] = h[t * 8 + k];
      pref[k] = acc;
      acc += cnt[k];
    }
    lsum[t] = acc;
  }
  __syncthreads();
  for (int o = 1; o < 256; o <<= 1) {
    int v = 0;
    if (t < 256 && t >= o) v = lsum[t - o];
    __syncthreads();
    if (t < 256 && t >= o) lsum[t] += v;
    __syncthreads();
  }
  if (t < 256) {
    int ex = (t == 0) ? 0 : lsum[t - 1];
#pragma unroll
    for (int k = 0; k < 8; ++k) {
      int g = bucket_base + ex + pref[k];
      int r = b * kRowsPerBkt + t * 8 + k;
      if (r < kN) rowptr[r] = g;
      h[t * 8 + k] = g;                 // global write cursor
    }
  }
  if (b == kNBKT - 1 && t == 0) rowptr[kN] = kNNZ;
  __syncthreads();
  // --- pass 2: place edges via LDS cursors ---
  for (int j = s + t; j < e; j += 1024) {
    int pay = tmp4[j];
    int rl = tmpr[j];
    int dst = atomicAdd(&h[rl], 1);
    edges[dst] = pay;
  }
}

// --- layer-3 pruning: mark rows read by the accumulators, degree-binned list.
__global__ void mark_rows(const int* __restrict__ users, const int* __restrict__ items,
                          int* __restrict__ mark) {
  int i = blockIdx.x * blockDim.x + threadIdx.x;
  if (i >= kB) return;
  mark[users[i]] = 1;
  mark[kUsers + items[i]] = 1;
}

__global__ void sub_hist(const int* __restrict__ rowptr, const int* __restrict__ mark,
                         int* __restrict__ dh) {
  __shared__ int h[64];
  int t = threadIdx.x;
  if (t < 64) h[t] = 0;
  __syncthreads();
  int i = blockIdx.x * 256 + t;
  if (i < kN && mark[i]) {
    int d = min(rowptr[i + 1] - rowptr[i], 63);
    atomicAdd(&h[d], 1);
  }
  __syncthreads();
  if (t < 64 && h[t]) atomicAdd(&dh[t], h[t]);
}

__global__ void deg_scan(int* __restrict__ dh, int* __restrict__ scnt) {  // 64 thr
  int t = threadIdx.x;
  int v = dh[t];
  int x = v;
  for (int o = 1; o < 64; o <<= 1) {
    int y = __shfl_up(x, o, 64);
    if (t >= o) x += y;
  }
  if (t == 63) *scnt = x;
  dh[t] = x - v;   // exclusive bin base
}

__global__ void sub_place(const int* __restrict__ rowptr, const int* __restrict__ mark,
                          int* __restrict__ dh, int* __restrict__ list) {
  __shared__ int h[64], base[64];
  int t = threadIdx.x;
  if (t < 64) h[t] = 0;
  __syncthreads();
  int i = blockIdx.x * 256 + t;
  int d = 0, lr = 0;
  bool okv = (i < kN) && mark[i];
  if (okv) {
    d = min(rowptr[i + 1] - rowptr[i], 63);
    lr = atomicAdd(&h[d], 1);
  }
  __syncthreads();
  if (t < 64) base[t] = h[t] ? atomicAdd(&dh[t], h[t]) : 0;
  __syncthreads();
  if (okv) list[base[d] + lr] = i;
}

// Union the subset rows' edge endpoints into mark: layer-2 output is only
// consumed at subset rows (acc_add) and at cols of subset rows' edges (spmm
// layer 3) -> spmm layer 2 can skip ~16% of rows.
__global__ void mark_cols(const int* __restrict__ list, const int* __restrict__ cnt,
                          const int* __restrict__ rowptr, const int* __restrict__ edges,
                          int* __restrict__ mark) {
  int p = blockIdx.x * blockDim.x + threadIdx.x;
  if (p >= *cnt) return;
  int r = list[p];
  int s = rowptr[r], e = rowptr[r + 1];
  for (int j = s; j < e; ++j) mark[edges[j] & 0x7FFFF] = 1;
}

// Convert concat(uemb, iemb) to fp8 e4m3, stored = 64*true. One thread per 8
// elems. nt loads: fp32 embeddings never re-read in bulk.
__global__ void to_fp8(const float* __restrict__ ue, const float* __restrict__ ie,
                       unsigned char* __restrict__ xq) {
  int t = blockIdx.x * blockDim.x + threadIdx.x;
  if (t >= kN * kD / 8) return;
  int row = t >> 3;
  int seg = t & 7;
  const float* src = (row < kUsers) ? (ue + (size_t)row * kD + seg * 8)
                                    : (ie + (size_t)(row - kUsers) * kD + seg * 8);
  v4f a = __builtin_nontemporal_load((const v4f*)src);
  v4f b = __builtin_nontemporal_load((const v4f*)src + 1);
  float f[8] = {a.x, a.y, a.z, a.w, b.x, b.y, b.z, b.w};
  unsigned int w0 = 0, w1 = 0;
#pragma unroll
  for (int k = 0; k < 4; ++k) w0 |= (unsigned int)enc(f[k] * 64.f) << (8 * k);
#pragma unroll
  for (int k = 0; k < 4; ++k) w1 |= (unsigned int)enc(f[4 + k] * 64.f) << (8 * k);
  v2i o; o.x = (int)w0; o.y = (int)w1;
  ((v2i*)xq)[t] = o;
}

// Reduction-free spmm, fp8 in / fp8 out (both scaled 64*true). One 8-lane
// group per row; lane l owns dims [8l,8l+8) = one 8-byte gather. Unroll-4
// edge prefetch. MODE 0: all rows. MODE 1: rows with aux[r]!=0. MODE 2: rows
// from aux list (subset). Identity row order for 0/1 (round-2 lesson).
// Round-6/8 counters: fetch-rate-bound ~3.67 TB/s, within ~10% of the
// 272 MB floor -> structure frozen.
template <int MODE>
__global__ __launch_bounds__(256, 8) void spmm(
    const int* __restrict__ rowptr, const int* __restrict__ edges,
    const unsigned char* __restrict__ x, unsigned char* __restrict__ yq,
    const int* __restrict__ aux, const int* __restrict__ cnt) {
  int t = threadIdx.x;
  int l = t & 7;                               // dim octet
  int wid = (blockIdx.x * 256 + t) >> 6;       // global wave id
  int g = (t >> 3) & 7;                        // group (row) within wave
  int p = wid * 8 + g;
  int r = -1;
  bool live = false;
  if (MODE == 2) {
    int n = *cnt;
    if (p < n) { r = aux[p]; live = true; }
  } else {
    if (p < kN) { r = p; live = (MODE == 0) || (aux[r] != 0); }
  }
  int s = 0, e = 0;
  if (live) { s = rowptr[r]; e = rowptr[r + 1]; }
  int mx = e - s;
#pragma unroll
  for (int m = 8; m <= 32; m <<= 1) mx = max(mx, __shfl_xor(mx, m, 64));
  float acc[8];
#pragma unroll
  for (int k = 0; k < 8; ++k) acc[k] = 0.f;
  int last = max(e - 1, 0);
  int j = s;
  int E0 = edges[min(j, last)];
  int E1 = edges[min(j + 1, last)];
  int E2 = edges[min(j + 2, last)];
  int E3 = edges[min(j + 3, last)];
  for (int it = 0; it < mx; it += 4) {
    float v0 = (j     < e) ? vdec(E0) : 0.f;
    float v1 = (j + 1 < e) ? vdec(E1) : 0.f;
    float v2 = (j + 2 < e) ? vdec(E2) : 0.f;
    float v3 = (j + 3 < e) ? vdec(E3) : 0.f;
    v2i h0 = ((const v2i*)(x + (size_t)(E0 & 0x7FFFF) * kD))[l];
    v2i h1 = ((const v2i*)(x + (size_t)(E1 & 0x7FFFF) * kD))[l];
    v2i h2 = ((const v2i*)(x + (size_t)(E2 & 0x7FFFF) * kD))[l];
    v2i h3 = ((const v2i*)(x + (size_t)(E3 & 0x7FFFF) * kD))[l];
    j += 4;
    E0 = edges[min(j, last)];                  // prefetch next quad (clamped)
    E1 = edges[min(j + 1, last)];
    E2 = edges[min(j + 2, last)];
    E3 = edges[min(j + 3, last)];
    float f[8];
    dec8(h0, f);
#pragma unroll
    for (int k = 0; k < 8; ++k) acc[k] = fmaf(v0, f[k], acc[k]);
    dec8(h1, f);
#pragma unroll
    for (int k = 0; k < 8; ++k) acc[k] = fmaf(v1, f[k], acc[k]);
    dec8(h2, f);
#pragma unroll
    for (int k = 0; k < 8; ++k) acc[k] = fmaf(v2, f[k], acc[k]);
    dec8(h3, f);
#pragma unroll
    for (int k = 0; k < 8; ++k) acc[k] = fmaf(v3, f[k], acc[k]);
  }
  if (live) {
    unsigned int w0 = 0, w1 = 0;
#pragma unroll
    for (int k = 0; k < 4; ++k) w0 |= (unsigned int)enc(acc[k]) << (8 * k);
#pragma unroll
    for (int k = 0; k < 4; ++k) w1 |= (unsigned int)enc(acc[4 + k]) << (8 * k);
    v2i o; o.x = (int)w0; o.y = (int)w1;
    ((v2i*)yq)[(size_t)r * 8 + l] = o;
  }
}

// acc = emb_gather + layer1 (fp8 layer output, stored = 64*true -> dec1)
__global__ void acc_add_init(const int* __restrict__ users, const int* __restrict__ items,
                             const float* __restrict__ uemb, const float* __restrict__ iemb,
                             const unsigned char* __restrict__ xq, float* __restrict__ uacc,
                             float* __restrict__ iacc) {
  int tid = blockIdx.x * blockDim.x + threadIdx.x;
  if (tid >= kB * kD) return;
  int b = tid >> 6, d = tid & 63;
  int u = users[b], iw = items[b];
  uacc[tid] = uemb[(size_t)u * kD + d] + dec1(xq[(size_t)u * kD + d]);
  iacc[tid] = iemb[(size_t)iw * kD + d] + dec1(xq[(size_t)(kUsers + iw) * kD + d]);
}

__global__ void acc_add(const int* __restrict__ users, const int* __restrict__ items,
                        const unsigned char* __restrict__ xq, float* __restrict__ uacc,
                        float* __restrict__ iacc) {
  int tid = blockIdx.x * blockDim.x + threadIdx.x;
  if (tid >= kB * kD) return;
  int b = tid >> 6, d = tid & 63;
  uacc[tid] += dec1(xq[(size_t)users[b] * kD + d]);
  iacc[tid] += dec1(xq[(size_t)(kUsers + items[b]) * kD + d]);
}

// layer-3 accumulate + dot + scale, fused
__global__ void acc_add_fin(const int* __restrict__ users, const int* __restrict__ items,
                            const unsigned char* __restrict__ xq, const float* __restrict__ uacc,
                            const float* __restrict__ iacc, float* __restrict__ out) {
  int tid = blockIdx.x * blockDim.x + threadIdx.x;
  if (tid >= kB * kD) return;
  int b = tid >> 6, d = tid & 63;
  float u = uacc[tid] + dec1(xq[(size_t)users[b] * kD + d]);
  float v = iacc[tid] + dec1(xq[(size_t)(kUsers + items[b]) * kD + d]);
  float p = u * v;
  for (int o = 32; o > 0; o >>= 1) p += __shfl_down(p, o, 64);
  if (d == 0) out[b] = p * 0.0625f;
}

}  // namespace

extern "C" void kernel_launch(void* const* d_in, const int* in_sizes, int n_in,
                              void* d_out, int out_size, void* d_ws, size_t ws_size,
                              hipStream_t stream) {
  const int*   users = (const int*)d_in[0];
  const int*   items = (const int*)d_in[1];
  const int*   erow  = (const int*)d_in[2];
  const int*   ecol  = (const int*)d_in[3];
  const float* evals = (const float*)d_in[4];
  const float* uemb  = (const float*)d_in[5];
  const float* iemb  = (const float*)d_in[6];
  float* out = (float*)d_out;

  char* ws = (char*)d_ws;
  size_t off = 0;
  auto take = [&](size_t bytes) -> char* {
    char* p = ws + off;
    off = (off + bytes + 255) & ~(size_t)255;
    return p;
  };
  int*    rowptr   = (int*)take((size_t)(kN + 1) * 4);
  int*    gpos     = (int*)take((kNBKT + 1) * 4);
  int*    dh       = (int*)take(256 * 4);    // DEDICATED (round-5 lesson)
  int*    mark     = (int*)take((size_t)kN * 4);
  int*    list     = (int*)take((size_t)kMaxSub * 4);
  int*    scnt     = (int*)take(256);
  int*    edges    = (int*)take((size_t)kNNZ * 4);                   // 20 MB packed
  int*    tmp4     = (int*)take((size_t)kNBKT * kCap * 4);           // 24 MB payload
  unsigned short* tmpr = (unsigned short*)take((size_t)kNBKT * kCap * 2);  // 12 MB rowlocal
  unsigned char* xq0 = (unsigned char*)take((size_t)kN * kD);        // fp8 ping (19.2 MB)
  unsigned char* xq1 = (unsigned char*)take((size_t)kN * kD);        // fp8 pong
  float*  uacc     = (float*)take((size_t)kB * kD * 4);
  float*  iacc     = (float*)take((size_t)kB * kD * 4);
  (void)ws_size; (void)in_sizes; (void)n_in; (void)out_size;

  const int nScatBlocks = (kNNZ + kSEPB - 1) / kSEPB;  // 1221
  const int nSpmmBlocks = (kN + 31) / 32;              // 8 rows/wave, 4 waves/block
  const int nSubBlocks  = (kMaxSub + 31) / 32;         // 1024
  const int nRowBlocks  = (kN + 255) / 256;            // 1172

  // --- CSR build: bucket sort, then ONE fused per-bucket hist+scan+place ---
  zero3<<<nRowBlocks, 256, 0, stream>>>(gpos, mark, dh, scnt);
  bucket_scatter<<<nScatBlocks, 256, 0, stream>>>(erow, ecol, evals, gpos, tmp4, tmpr);
  build_csr<<<kNBKT, 1024, 0, stream>>>(gpos, tmp4, tmpr, rowptr, edges);

  // --- layer-3 row subset, degree-binned; then union its edge endpoints into
  //     mark for the layer-2 row mask ---
  mark_rows<<<(kB + 255) / 256, 256, 0, stream>>>(users, items, mark);
  sub_hist<<<nRowBlocks, 256, 0, stream>>>(rowptr, mark, dh);
  deg_scan<<<1, 64, 0, stream>>>(dh, scnt);
  sub_place<<<nRowBlocks, 256, 0, stream>>>(rowptr, mark, dh, list);
  mark_cols<<<(kMaxSub + 255) / 256, 256, 0, stream>>>(list, scnt, rowptr, edges, mark);

  // --- fp8 copy of concat embeddings ---
  to_fp8<<<(kN * kD / 8 + 255) / 256, 256, 0, stream>>>(uemb, iemb, xq0);
  // --- 3 propagation layers; fp8 ping-pong; layer 2 masked, layer 3 subset ---
  spmm<0><<<nSpmmBlocks, 256, 0, stream>>>(rowptr, edges, xq0, xq1, nullptr, nullptr);
  acc_add_init<<<(kB * kD) / 256, 256, 0, stream>>>(users, items, uemb, iemb, xq1, uacc, iacc);
  spmm<1><<<nSpmmBlocks, 256, 0, stream>>>(rowptr, edges, xq1, xq0, mark, nullptr);
  acc_add<<<(kB * kD) / 256, 256, 0, stream>>>(users, items, xq0, uacc, iacc);
  spmm<2><<<nSubBlocks, 256, 0, stream>>>(rowptr, edges, xq0, xq1, list, scnt);
  acc_add_fin<<<(kB * kD) / 256, 256, 0, stream>>>(users, items, xq1, uacc, iacc, out);
}

// Round 10
// 460.736 us; speedup vs baseline: 2.0693x; 1.0484x over previous
//
#include <hip/hip_runtime.h>
#include <hip/hip_fp16.h>
#include <hip/hip_fp8.h>

namespace {

constexpr int kUsers = 100000;
constexpr int kItems = 200000;
constexpr int kN     = kUsers + kItems;   // 300000
constexpr int kD     = 64;
constexpr int kNNZ   = 5000000;
constexpr int kB     = 16384;
constexpr int kRowsPerBkt = 2048;                       // rows per coarse bucket
constexpr int kNBKT  = (kN + kRowsPerBkt - 1) / kRowsPerBkt;  // 147
constexpr int kSEPB  = 4096;                            // edges per bucket_scatter block
constexpr int kCap   = 40960;                           // slots/bucket (mean 34133, sd 185)
constexpr int kMaxSub = 2 * kB;                         // upper bound on marked rows

typedef int   v2i __attribute__((ext_vector_type(2)));
typedef float v4f __attribute__((ext_vector_type(4)));

// --- fp8 e4m3 storage: buffers hold 64*true_value. Native v_cvt_pk_f32_fp8
// decode (round-6: VALUBusy 71->46%, spmm -15%). Bit-trick fallback yields
// stored/256, patched by kValScale on the edge weight. Builtins return PLAIN
// float vectors -> index with [].
#if defined(__has_builtin)
#if __has_builtin(__builtin_amdgcn_cvt_pk_f32_fp8) && __has_builtin(__builtin_amdgcn_cvt_f32_fp8)
#define NATIVE_FP8 1
#endif
#endif
#ifndef NATIVE_FP8
#define NATIVE_FP8 0
#endif

constexpr float kValScale = NATIVE_FP8 ? 1.0f : 256.0f;

__device__ inline void dec8(v2i h, float* f) {
#if NATIVE_FP8
  auto a0 = __builtin_amdgcn_cvt_pk_f32_fp8(h.x, false);
  auto a1 = __builtin_amdgcn_cvt_pk_f32_fp8(h.x, true);
  auto a2 = __builtin_amdgcn_cvt_pk_f32_fp8(h.y, false);
  auto a3 = __builtin_amdgcn_cvt_pk_f32_fp8(h.y, true);
  f[0] = a0[0]; f[1] = a0[1]; f[2] = a1[0]; f[3] = a1[1];
  f[4] = a2[0]; f[5] = a2[1]; f[6] = a3[0]; f[7] = a3[1];
#else
  unsigned int ws[2] = {(unsigned int)h.x, (unsigned int)h.y};
#pragma unroll
  for (int q = 0; q < 2; ++q) {
    unsigned int w = ws[q];
    unsigned int a = ((w & 0x007f007fu) << 7) | ((w & 0x00800080u) << 8);
    unsigned int b = (((w >> 8) & 0x007f007fu) << 7) | (((w >> 8) & 0x00800080u) << 8);
    float2 e = __half22float2(*reinterpret_cast<const __half2*>(&a));
    float2 o = __half22float2(*reinterpret_cast<const __half2*>(&b));
    f[4 * q + 0] = e.x; f[4 * q + 1] = o.x; f[4 * q + 2] = e.y; f[4 * q + 3] = o.y;
  }
#endif
}

__device__ inline float dec1(unsigned char b) {  // stored(=64*true) -> true
#if NATIVE_FP8
  return __builtin_amdgcn_cvt_f32_fp8((int)b, 0) * 0.015625f;
#else
  unsigned int hb = ((b & 0x7fu) << 7) | ((b & 0x80u) << 8);
  return __half2float(__ushort_as_half((unsigned short)hb)) * 4.0f;
#endif
}

__device__ inline unsigned char enc(float f) { __hip_fp8_e4m3 q(f); return q.__x; }

// packed edge: bits[18:0] = col, bits[31:19] = val13 (fp16 bits rounded to
// 5-exp + 8-mantissa; vals >= 0 so no sign bit). rel err 2^-9.
__device__ inline float vdec(int w) {
  return __half2float(__ushort_as_half((unsigned short)((w >> 17) & 0x7FFC))) * kValScale;
}

__global__ void zero3(int* __restrict__ gpos, int* __restrict__ mark,
                      int* __restrict__ scnt) {
  int i = blockIdx.x * blockDim.x + threadIdx.x;
  if (i < kN) mark[i] = 0;
  if (i < kNBKT + 1) gpos[i] = 0;
  if (i == 0) scnt[0] = 0;
}

// Counting-sort partition of 4096 edges into 147 coarse buckets; per-wave LDS
// histograms (4x147) cut same-address atomic serialization 4x. LDS staging so
// tmp writes go out in coalesced bucket-run bursts. NO per-row global atomics
// (round-7 lesson: 5M device-scope atomics = memory-side RMW = 302 MB MALL
// write + 350 us; counting stays in LDS / per-bucket kernels). tmp split:
// 4 B payload + 2 B rowlocal (6 B/edge).
__global__ void bucket_scatter(const int* __restrict__ row, const int* __restrict__ col,
                               const float* __restrict__ val, int* __restrict__ gpos,
                               int* __restrict__ tmp4, unsigned short* __restrict__ tmpr) {
  __shared__ int hcnt[4][kNBKT];   // per-wave counts -> wave-exclusive offsets
  __shared__ int lofs[kNBKT];
  __shared__ int hbase[kNBKT];
  __shared__ int lds[256];
  __shared__ int sp[kSEPB];              // payload stage
  __shared__ unsigned short sr[kSEPB];   // rowlocal stage
  __shared__ unsigned short sb[kSEPB];   // bucket stage
  int t = threadIdx.x;
  int wv = t >> 6;
  long base = (long)blockIdx.x * kSEPB;
  int valid = (int)min((long)kSEPB, (long)kNNZ - base);
  for (int i = t; i < kNBKT; i += 256) {
    hcnt[0][i] = 0; hcnt[1][i] = 0; hcnt[2][i] = 0; hcnt[3][i] = 0;
  }
  __syncthreads();
  int py[16], bk[16], rl[16], rk[16];
  bool ok[16];
#pragma unroll
  for (int j = 0; j < 16; ++j) {
    long i = base + j * 256 + t;
    ok[j] = (i < kNNZ);
    if (ok[j]) {
      int r = __builtin_nontemporal_load(row + i);
      int c = __builtin_nontemporal_load(col + i);
      float v = __builtin_nontemporal_load(val + i);
      bk[j] = r >> 11;
      rl[j] = r & 2047;
      unsigned short hb = __half_as_ushort(__float2half_rn(v));
      int v13 = ((int)hb + 2) >> 2;              // round to exp5+man8
      py[j] = c | (v13 << 19);
      rk[j] = atomicAdd(&hcnt[wv][bk[j]], 1);
    }
  }
  __syncthreads();
  int own = 0;
  if (t < kNBKT) {
    int c0 = hcnt[0][t], c1 = hcnt[1][t], c2 = hcnt[2][t], c3 = hcnt[3][t];
    hcnt[0][t] = 0; hcnt[1][t] = c0; hcnt[2][t] = c0 + c1; hcnt[3][t] = c0 + c1 + c2;
    own = c0 + c1 + c2 + c3;
  }
  lds[t] = own;
  __syncthreads();
  for (int o = 1; o < 256; o <<= 1) {
    int x = (t >= o) ? lds[t - o] : 0;
    __syncthreads();
    if (t >= o) lds[t] += x;
    __syncthreads();
  }
  if (t < kNBKT) {
    lofs[t] = lds[t] - own;
    hbase[t] = t * kCap + atomicAdd(&gpos[t], own);
  }
  __syncthreads();
#pragma unroll
  for (int j = 0; j < 16; ++j) {
    if (ok[j]) {
      int pos = lofs[bk[j]] + hcnt[wv][bk[j]] + rk[j];
      sp[pos] = py[j];
      sr[pos] = (unsigned short)rl[j];
      sb[pos] = (unsigned short)bk[j];
    }
  }
  __syncthreads();
#pragma unroll
  for (int j = 0; j < 16; ++j) {
    int pos = t + j * 256;
    if (pos < valid) {
      int b = sb[pos];
      int w = hbase[b] + (pos - lofs[b]);
      tmp4[w] = sp[pos];
      tmpr[w] = sr[pos];
    }
  }
}

// Grid = 2*kNBKT (TWO blocks per bucket, round-10: 147 blocks left 43% of CUs
// idle). Each block re-derives the full-bucket hist (duplicated 2 B/edge read,
// cheap) and the 2048-row scan, writes FINAL rowptr (half 0 only), then places
// ONLY the edges whose row falls in its 1024-row half. Write windows per block
// are contiguous, disjoint ~68 KB ranges -> single-XCD writer per cache line
// preserved (round-7 lesson: multi-XCD partial lines = 15x write
// amplification; round-8/9 verified the fix).
__global__ __launch_bounds__(1024) void build_csr(
    const int* __restrict__ gpos, const int* __restrict__ tmp4,
    const unsigned short* __restrict__ tmpr, int* __restrict__ rowptr,
    int* __restrict__ edges) {
  __shared__ int h[kRowsPerBkt];     // hist -> global cursors
  __shared__ int lsum[256];
  __shared__ int gscan[256];
  int b = blockIdx.x >> 1;
  int half = blockIdx.x & 1;
  int t = threadIdx.x;
  // --- bucket base: in-block inclusive scan of gpos[0..kNBKT) (147 values) ---
  if (t < 256) gscan[t] = (t < kNBKT) ? gpos[t] : 0;
  for (int i = t; i < kRowsPerBkt; i += 1024) h[i] = 0;
  __syncthreads();
  for (int o = 1; o < 256; o <<= 1) {
    int v = 0;
    if (t < 256 && t >= o) v = gscan[t - o];
    __syncthreads();
    if (t < 256 && t >= o) gscan[t] += v;
    __syncthreads();
  }
  int bucket_base = (b == 0) ? 0 : gscan[b - 1];
  int s = b * kCap;
  int e = s + gpos[b];
  // --- pass 1: full-bucket row histogram (2 B/edge) ---
  for (int j = s + t; j < e; j += 1024) atomicAdd(&h[tmpr[j]], 1);
  __syncthreads();
  // --- scan 2048 rows (256 threads x 8), write FINAL rowptr, make cursors ---
  int cnt[8], pref[8];
  if (t < 256) {
    int acc = 0;
#pragma unroll
    for (int k = 0; k < 8; ++k) {
      cnt[k] = h[t * 8 + k];
      pref[k] = acc;
      acc += cnt[k];
    }
    lsum[t] = acc;
  }
  __syncthreads();
  for (int o = 1; o < 256; o <<= 1) {
    int v = 0;
    if (t < 256 && t >= o) v = lsum[t - o];
    __syncthreads();
    if (t < 256 && t >= o) lsum[t] += v;
    __syncthreads();
  }
  if (t < 256) {
    int ex = (t == 0) ? 0 : lsum[t - 1];
#pragma unroll
    for (int k = 0; k < 8; ++k) {
      int g = bucket_base + ex + pref[k];
      int r = b * kRowsPerBkt + t * 8 + k;
      if (half == 0 && r < kN) rowptr[r] = g;   // one writer per rowptr entry
      h[t * 8 + k] = g;                         // global write cursor
    }
  }
  if (blockIdx.x == 0 && t == 0) rowptr[kN] = kNNZ;
  __syncthreads();
  // --- pass 2: place only this half's rows via LDS cursors ---
  int lo = half << 10, hi = lo + 1024;
  for (int j = s + t; j < e; j += 1024) {
    int rl = tmpr[j];
    if (rl >= lo && rl < hi) {
      int dst = atomicAdd(&h[rl], 1);
      edges[dst] = tmp4[j];
    }
  }
}

// --- layer-3 pruning: mark rows read by the finalize gather, ballot-compact
// them into list (one global atomic per block), then union their edge
// endpoints into mark for the layer-2 row mask.
__global__ void mark_rows(const int* __restrict__ users, const int* __restrict__ items,
                          int* __restrict__ mark) {
  int i = blockIdx.x * blockDim.x + threadIdx.x;
  if (i >= kB) return;
  mark[users[i]] = 1;
  mark[kUsers + items[i]] = 1;
}

__global__ void compact_rows(const int* __restrict__ mark, int* __restrict__ list,
                             int* __restrict__ cnt) {
  __shared__ int wbase[4];
  int t = threadIdx.x;
  int i = blockIdx.x * 256 + t;
  bool m = (i < kN) && mark[i];
  unsigned long long bal = __ballot(m);
  int wv = t >> 6, ln = t & 63;
  if (ln == 0) wbase[wv] = __popcll(bal);
  __syncthreads();
  if (t == 0) {
    int tot = wbase[0] + wbase[1] + wbase[2] + wbase[3];
    int base = tot ? atomicAdd(cnt, tot) : 0;
    int p = base;
#pragma unroll
    for (int w = 0; w < 4; ++w) { int c = wbase[w]; wbase[w] = p; p += c; }
  }
  __syncthreads();
  if (m) {
    int rank = __popcll(bal & ((1ull << ln) - 1));
    list[wbase[wv] + rank] = i;
  }
}

// Union the subset rows' edge endpoints into mark: layer-2 output is only
// consumed at subset rows (finalize) and at cols of subset rows' edges (spmm
// layer 3) -> spmm layer 2 can skip ~16% of rows.
__global__ void mark_cols(const int* __restrict__ list, const int* __restrict__ cnt,
                          const int* __restrict__ rowptr, const int* __restrict__ edges,
                          int* __restrict__ mark) {
  int p = blockIdx.x * blockDim.x + threadIdx.x;
  if (p >= *cnt) return;
  int r = list[p];
  int s = rowptr[r], e = rowptr[r + 1];
  for (int j = s; j < e; ++j) mark[edges[j] & 0x7FFFF] = 1;
}

// Convert concat(uemb, iemb) to fp8 e4m3, stored = 64*true. One thread per 8
// elems. nt loads: fp32 embeddings never re-read in bulk.
__global__ void to_fp8(const float* __restrict__ ue, const float* __restrict__ ie,
                       unsigned char* __restrict__ xq) {
  int t = blockIdx.x * blockDim.x + threadIdx.x;
  if (t >= kN * kD / 8) return;
  int row = t >> 3;
  int seg = t & 7;
  const float* src = (row < kUsers) ? (ue + (size_t)row * kD + seg * 8)
                                    : (ie + (size_t)(row - kUsers) * kD + seg * 8);
  v4f a = __builtin_nontemporal_load((const v4f*)src);
  v4f b = __builtin_nontemporal_load((const v4f*)src + 1);
  float f[8] = {a.x, a.y, a.z, a.w, b.x, b.y, b.z, b.w};
  unsigned int w0 = 0, w1 = 0;
#pragma unroll
  for (int k = 0; k < 4; ++k) w0 |= (unsigned int)enc(f[k] * 64.f) << (8 * k);
#pragma unroll
  for (int k = 0; k < 4; ++k) w1 |= (unsigned int)enc(f[4 + k] * 64.f) << (8 * k);
  v2i o; o.x = (int)w0; o.y = (int)w1;
  ((v2i*)xq)[t] = o;
}

// Reduction-free spmm, fp8 in / fp8 out (both scaled 64*true). One 8-lane
// group per row; lane l owns dims [8l,8l+8) = one 8-byte gather. Unroll-4
// edge prefetch. MODE 0: all rows. MODE 1: rows with aux[r]!=0. MODE 2: rows
// from aux list (subset). Identity row order for 0/1 (round-2 lesson).
// Round-6/8/9 counters: fetch-rate-bound ~3.67 TB/s, within ~10% of the
// 272 MB floor -> structure frozen.
template <int MODE>
__global__ __launch_bounds__(256, 8) void spmm(
    const int* __restrict__ rowptr, const int* __restrict__ edges,
    const unsigned char* __restrict__ x, unsigned char* __restrict__ yq,
    const int* __restrict__ aux, const int* __restrict__ cnt) {
  int t = threadIdx.x;
  int l = t & 7;                               // dim octet
  int wid = (blockIdx.x * 256 + t) >> 6;       // global wave id
  int g = (t >> 3) & 7;                        // group (row) within wave
  int p = wid * 8 + g;
  int r = -1;
  bool live = false;
  if (MODE == 2) {
    int n = *cnt;
    if (p < n) { r = aux[p]; live = true; }
  } else {
    if (p < kN) { r = p; live = (MODE == 0) || (aux[r] != 0); }
  }
  int s = 0, e = 0;
  if (live) { s = rowptr[r]; e = rowptr[r + 1]; }
  int mx = e - s;
#pragma unroll
  for (int m = 8; m <= 32; m <<= 1) mx = max(mx, __shfl_xor(mx, m, 64));
  float acc[8];
#pragma unroll
  for (int k = 0; k < 8; ++k) acc[k] = 0.f;
  int last = max(e - 1, 0);
  int j = s;
  int E0 = edges[min(j, last)];
  int E1 = edges[min(j + 1, last)];
  int E2 = edges[min(j + 2, last)];
  int E3 = edges[min(j + 3, last)];
  for (int it = 0; it < mx; it += 4) {
    float v0 = (j     < e) ? vdec(E0) : 0.f;
    float v1 = (j + 1 < e) ? vdec(E1) : 0.f;
    float v2 = (j + 2 < e) ? vdec(E2) : 0.f;
    float v3 = (j + 3 < e) ? vdec(E3) : 0.f;
    v2i h0 = ((const v2i*)(x + (size_t)(E0 & 0x7FFFF) * kD))[l];
    v2i h1 = ((const v2i*)(x + (size_t)(E1 & 0x7FFFF) * kD))[l];
    v2i h2 = ((const v2i*)(x + (size_t)(E2 & 0x7FFFF) * kD))[l];
    v2i h3 = ((const v2i*)(x + (size_t)(E3 & 0x7FFFF) * kD))[l];
    j += 4;
    E0 = edges[min(j, last)];                  // prefetch next quad (clamped)
    E1 = edges[min(j + 1, last)];
    E2 = edges[min(j + 2, last)];
    E3 = edges[min(j + 3, last)];
    float f[8];
    dec8(h0, f);
#pragma unroll
    for (int k = 0; k < 8; ++k) acc[k] = fmaf(v0, f[k], acc[k]);
    dec8(h1, f);
#pragma unroll
    for (int k = 0; k < 8; ++k) acc[k] = fmaf(v1, f[k], acc[k]);
    dec8(h2, f);
#pragma unroll
    for (int k = 0; k < 8; ++k) acc[k] = fmaf(v2, f[k], acc[k]);
    dec8(h3, f);
#pragma unroll
    for (int k = 0; k < 8; ++k) acc[k] = fmaf(v3, f[k], acc[k]);
  }
  if (live) {
    unsigned int w0 = 0, w1 = 0;
#pragma unroll
    for (int k = 0; k < 4; ++k) w0 |= (unsigned int)enc(acc[k]) << (8 * k);
#pragma unroll
    for (int k = 0; k < 4; ++k) w1 |= (unsigned int)enc(acc[4 + k]) << (8 * k);
    v2i o; o.x = (int)w0; o.y = (int)w1;
    ((v2i*)yq)[(size_t)r * 8 + l] = o;
  }
}

// out[b] = dot(emb_u + l1 + l2 + l3, emb_i + l1 + l2 + l3) / 16.
// Replaces acc_add_init + acc_add + acc_add_fin (round-10): identical fp32
// add order ((emb+l1)+l2)+l3, no uacc/iacc round-trips.
__global__ void finalize(const int* __restrict__ users, const int* __restrict__ items,
                         const float* __restrict__ uemb, const float* __restrict__ iemb,
                         const unsigned char* __restrict__ l1,
                         const unsigned char* __restrict__ l2,
                         const unsigned char* __restrict__ l3, float* __restrict__ out) {
  int tid = blockIdx.x * blockDim.x + threadIdx.x;
  if (tid >= kB * kD) return;
  int b = tid >> 6, d = tid & 63;
  size_t u = (size_t)users[b] * kD + d;
  size_t iw = (size_t)(kUsers + items[b]) * kD + d;
  float us = uemb[(size_t)users[b] * kD + d] + dec1(l1[u]) + dec1(l2[u]) + dec1(l3[u]);
  float vs = iemb[(size_t)items[b] * kD + d] + dec1(l1[iw]) + dec1(l2[iw]) + dec1(l3[iw]);
  float p = us * vs;
  for (int o = 32; o > 0; o >>= 1) p += __shfl_down(p, o, 64);
  if (d == 0) out[b] = p * 0.0625f;
}

}  // namespace

extern "C" void kernel_launch(void* const* d_in, const int* in_sizes, int n_in,
                              void* d_out, int out_size, void* d_ws, size_t ws_size,
                              hipStream_t stream) {
  const int*   users = (const int*)d_in[0];
  const int*   items = (const int*)d_in[1];
  const int*   erow  = (const int*)d_in[2];
  const int*   ecol  = (const int*)d_in[3];
  const float* evals = (const float*)d_in[4];
  const float* uemb  = (const float*)d_in[5];
  const float* iemb  = (const float*)d_in[6];
  float* out = (float*)d_out;

  char* ws = (char*)d_ws;
  size_t off = 0;
  auto take = [&](size_t bytes) -> char* {
    char* p = ws + off;
    off = (off + bytes + 255) & ~(size_t)255;
    return p;
  };
  int*    rowptr   = (int*)take((size_t)(kN + 1) * 4);
  int*    gpos     = (int*)take((kNBKT + 1) * 4);
  int*    mark     = (int*)take((size_t)kN * 4);
  int*    list     = (int*)take((size_t)kMaxSub * 4);
  int*    scnt     = (int*)take(256);
  int*    edges    = (int*)take((size_t)kNNZ * 4);                   // 20 MB packed
  int*    tmp4     = (int*)take((size_t)kNBKT * kCap * 4);           // 24 MB payload
  unsigned short* tmpr = (unsigned short*)take((size_t)kNBKT * kCap * 2);  // 12 MB rowlocal
  unsigned char* xq0 = (unsigned char*)take((size_t)kN * kD);        // emb, then l3
  unsigned char* xq1 = (unsigned char*)take((size_t)kN * kD);        // l1
  unsigned char* xq2 = (unsigned char*)take((size_t)kN * kD);        // l2
  (void)ws_size; (void)in_sizes; (void)n_in; (void)out_size;

  const int nScatBlocks = (kNNZ + kSEPB - 1) / kSEPB;  // 1221
  const int nSpmmBlocks = (kN + 31) / 32;              // 8 rows/wave, 4 waves/block
  const int nSubBlocks  = (kMaxSub + 31) / 32;         // 1024
  const int nRowBlocks  = (kN + 255) / 256;            // 1172

  // --- CSR build: bucket sort, then fused per-half-bucket hist+scan+place ---
  zero3<<<nRowBlocks, 256, 0, stream>>>(gpos, mark, scnt);
  bucket_scatter<<<nScatBlocks, 256, 0, stream>>>(erow, ecol, evals, gpos, tmp4, tmpr);
  build_csr<<<2 * kNBKT, 1024, 0, stream>>>(gpos, tmp4, tmpr, rowptr, edges);

  // --- layer-3 row subset (ballot compact); union its edge endpoints into
  //     mark for the layer-2 row mask ---
  mark_rows<<<(kB + 255) / 256, 256, 0, stream>>>(users, items, mark);
  compact_rows<<<nRowBlocks, 256, 0, stream>>>(mark, list, scnt);
  mark_cols<<<(kMaxSub + 255) / 256, 256, 0, stream>>>(list, scnt, rowptr, edges, mark);

  // --- fp8 copy of concat embeddings ---
  to_fp8<<<(kN * kD / 8 + 255) / 256, 256, 0, stream>>>(uemb, iemb, xq0);
  // --- 3 propagation layers: xq0(emb)->xq1(l1)->xq2(l2,masked)->xq0(l3,subset)
  //     (xq0's emb copy is dead after spmm<0>; finalize uses fp32 emb) ---
  spmm<0><<<nSpmmBlocks, 256, 0, stream>>>(rowptr, edges, xq0, xq1, nullptr, nullptr);
  spmm<1><<<nSpmmBlocks, 256, 0, stream>>>(rowptr, edges, xq1, xq2, mark, nullptr);
  spmm<2><<<nSubBlocks, 256, 0, stream>>>(rowptr, edges, xq2, xq0, list, scnt);
  finalize<<<(kB * kD) / 256, 256, 0, stream>>>(users, items, uemb, iemb,
                                                xq1, xq2, xq0, out);
}

// Round 11
// 440.979 us; speedup vs baseline: 2.1620x; 1.0448x over previous
//
#include <hip/hip_runtime.h>
#include <hip/hip_fp16.h>
#include <hip/hip_fp8.h>

namespace {

constexpr int kUsers = 100000;
constexpr int kItems = 200000;
constexpr int kN     = kUsers + kItems;   // 300000
constexpr int kD     = 64;
constexpr int kNNZ   = 5000000;
constexpr int kB     = 16384;
constexpr int kRowsPerBkt = 2048;                       // rows per coarse bucket
constexpr int kNBKT  = (kN + kRowsPerBkt - 1) / kRowsPerBkt;  // 147
constexpr int kSEPB  = 4096;                            // edges per bucket_scatter block
constexpr int kCap   = 40960;                           // slots/bucket (mean 34133, sd 185)
constexpr int kMaxSub = 2 * kB;                         // upper bound on marked rows

// launch-fusion block counts (round-11: 11 launches -> 7; round-9 showed
// ~8-10 us per launch on this harness)
constexpr int kZeroBlocks  = (kN + 255) / 256;          // 1172
constexpr int kFp8Blocks   = (kN * kD / 8 + 255) / 256; // 9375
constexpr int kScatBlocks  = (kNNZ + kSEPB - 1) / kSEPB;// 1221
constexpr int kMarkBlocks  = (kB + 255) / 256;          // 64
constexpr int kBuildBlocks = 2 * kNBKT;                 // 294
constexpr int kCompBlocks  = (kN + 1023) / 1024;        // 293
constexpr int kSpmmMain    = (kN + 31) / 32;            // 9375
constexpr int kMCBlocks    = kMaxSub / 256;             // 128

typedef int   v2i __attribute__((ext_vector_type(2)));
typedef float v4f __attribute__((ext_vector_type(4)));

// --- fp8 e4m3 storage: buffers hold 64*true_value. Native v_cvt_pk_f32_fp8
// decode (round-6: VALUBusy 71->46%, spmm -15%). Bit-trick fallback yields
// stored/256, patched by kValScale on the edge weight. Builtins return PLAIN
// float vectors -> index with [].
#if defined(__has_builtin)
#if __has_builtin(__builtin_amdgcn_cvt_pk_f32_fp8) && __has_builtin(__builtin_amdgcn_cvt_f32_fp8)
#define NATIVE_FP8 1
#endif
#endif
#ifndef NATIVE_FP8
#define NATIVE_FP8 0
#endif

constexpr float kValScale = NATIVE_FP8 ? 1.0f : 256.0f;

__device__ inline void dec8(v2i h, float* f) {
#if NATIVE_FP8
  auto a0 = __builtin_amdgcn_cvt_pk_f32_fp8(h.x, false);
  auto a1 = __builtin_amdgcn_cvt_pk_f32_fp8(h.x, true);
  auto a2 = __builtin_amdgcn_cvt_pk_f32_fp8(h.y, false);
  auto a3 = __builtin_amdgcn_cvt_pk_f32_fp8(h.y, true);
  f[0] = a0[0]; f[1] = a0[1]; f[2] = a1[0]; f[3] = a1[1];
  f[4] = a2[0]; f[5] = a2[1]; f[6] = a3[0]; f[7] = a3[1];
#else
  unsigned int ws[2] = {(unsigned int)h.x, (unsigned int)h.y};
#pragma unroll
  for (int q = 0; q < 2; ++q) {
    unsigned int w = ws[q];
    unsigned int a = ((w & 0x007f007fu) << 7) | ((w & 0x00800080u) << 8);
    unsigned int b = (((w >> 8) & 0x007f007fu) << 7) | (((w >> 8) & 0x00800080u) << 8);
    float2 e = __half22float2(*reinterpret_cast<const __half2*>(&a));
    float2 o = __half22float2(*reinterpret_cast<const __half2*>(&b));
    f[4 * q + 0] = e.x; f[4 * q + 1] = o.x; f[4 * q + 2] = e.y; f[4 * q + 3] = o.y;
  }
#endif
}

__device__ inline float dec1(unsigned char b) {  // stored(=64*true) -> true
#if NATIVE_FP8
  return __builtin_amdgcn_cvt_f32_fp8((int)b, 0) * 0.015625f;
#else
  unsigned int hb = ((b & 0x7fu) << 7) | ((b & 0x80u) << 8);
  return __half2float(__ushort_as_half((unsigned short)hb)) * 4.0f;
#endif
}

__device__ inline unsigned char enc(float f) { __hip_fp8_e4m3 q(f); return q.__x; }

// packed edge: bits[18:0] = col, bits[31:19] = val13 (fp16 bits rounded to
// 5-exp + 8-mantissa; vals >= 0 so no sign bit). rel err 2^-9.
__device__ inline float vdec(int w) {
  return __half2float(__ushort_as_half((unsigned short)((w >> 17) & 0x7FFC))) * kValScale;
}

// Launch 1: zeroing (blocks < kZeroBlocks) || fp8 conversion of concat
// embeddings (rest). Independent workloads fused to cut a launch.
__global__ void prep(int* __restrict__ gpos, int* __restrict__ mark,
                     int* __restrict__ scnt, const float* __restrict__ ue,
                     const float* __restrict__ ie, unsigned char* __restrict__ xq) {
  int bid = blockIdx.x;
  if (bid < kZeroBlocks) {
    int i = bid * 256 + threadIdx.x;
    if (i < kN) mark[i] = 0;
    if (i < kNBKT + 1) gpos[i] = 0;
    if (i == 0) scnt[0] = 0;
    return;
  }
  int t = (bid - kZeroBlocks) * 256 + threadIdx.x;
  if (t >= kN * kD / 8) return;
  int row = t >> 3;
  int seg = t & 7;
  const float* src = (row < kUsers) ? (ue + (size_t)row * kD + seg * 8)
                                    : (ie + (size_t)(row - kUsers) * kD + seg * 8);
  v4f a = __builtin_nontemporal_load((const v4f*)src);
  v4f b = __builtin_nontemporal_load((const v4f*)src + 1);
  float f[8] = {a.x, a.y, a.z, a.w, b.x, b.y, b.z, b.w};
  unsigned int w0 = 0, w1 = 0;
#pragma unroll
  for (int k = 0; k < 4; ++k) w0 |= (unsigned int)enc(f[k] * 64.f) << (8 * k);
#pragma unroll
  for (int k = 0; k < 4; ++k) w1 |= (unsigned int)enc(f[4 + k] * 64.f) << (8 * k);
  v2i o; o.x = (int)w0; o.y = (int)w1;
  ((v2i*)xq)[t] = o;
}

// Launch 2: counting-sort partition of 4096 edges into 147 coarse buckets
// (blocks < kScatBlocks) || mark_rows (tail blocks; needs prep's zeroed mark).
// Per-wave LDS histograms (4x147) cut same-address atomic serialization 4x;
// LDS staging -> coalesced bucket-run bursts. NO per-row global atomics
// (round-7 lesson: 5M device-scope atomics = memory-side RMW = 302 MB MALL
// write). tmp split: 4 B payload + 2 B rowlocal (6 B/edge).
__global__ void bucket_scatter(const int* __restrict__ row, const int* __restrict__ col,
                               const float* __restrict__ val, int* __restrict__ gpos,
                               int* __restrict__ tmp4, unsigned short* __restrict__ tmpr,
                               const int* __restrict__ users, const int* __restrict__ items,
                               int* __restrict__ mark) {
  if ((int)blockIdx.x >= kScatBlocks) {   // --- mark_rows tail ---
    int i = ((int)blockIdx.x - kScatBlocks) * 256 + threadIdx.x;
    if (i < kB) {
      mark[users[i]] = 1;
      mark[kUsers + items[i]] = 1;
    }
    return;
  }
  __shared__ int hcnt[4][kNBKT];   // per-wave counts -> wave-exclusive offsets
  __shared__ int lofs[kNBKT];
  __shared__ int hbase[kNBKT];
  __shared__ int lds[256];
  __shared__ int sp[kSEPB];              // payload stage
  __shared__ unsigned short sr[kSEPB];   // rowlocal stage
  __shared__ unsigned short sb[kSEPB];   // bucket stage
  int t = threadIdx.x;
  int wv = t >> 6;
  long base = (long)blockIdx.x * kSEPB;
  int valid = (int)min((long)kSEPB, (long)kNNZ - base);
  for (int i = t; i < kNBKT; i += 256) {
    hcnt[0][i] = 0; hcnt[1][i] = 0; hcnt[2][i] = 0; hcnt[3][i] = 0;
  }
  __syncthreads();
  int py[16], bk[16], rl[16], rk[16];
  bool ok[16];
#pragma unroll
  for (int j = 0; j < 16; ++j) {
    long i = base + j * 256 + t;
    ok[j] = (i < kNNZ);
    if (ok[j]) {
      int r = __builtin_nontemporal_load(row + i);
      int c = __builtin_nontemporal_load(col + i);
      float v = __builtin_nontemporal_load(val + i);
      bk[j] = r >> 11;
      rl[j] = r & 2047;
      unsigned short hb = __half_as_ushort(__float2half_rn(v));
      int v13 = ((int)hb + 2) >> 2;              // round to exp5+man8
      py[j] = c | (v13 << 19);
      rk[j] = atomicAdd(&hcnt[wv][bk[j]], 1);
    }
  }
  __syncthreads();
  int own = 0;
  if (t < kNBKT) {
    int c0 = hcnt[0][t], c1 = hcnt[1][t], c2 = hcnt[2][t], c3 = hcnt[3][t];
    hcnt[0][t] = 0; hcnt[1][t] = c0; hcnt[2][t] = c0 + c1; hcnt[3][t] = c0 + c1 + c2;
    own = c0 + c1 + c2 + c3;
  }
  lds[t] = own;
  __syncthreads();
  for (int o = 1; o < 256; o <<= 1) {
    int x = (t >= o) ? lds[t - o] : 0;
    __syncthreads();
    if (t >= o) lds[t] += x;
    __syncthreads();
  }
  if (t < kNBKT) {
    lofs[t] = lds[t] - own;
    hbase[t] = t * kCap + atomicAdd(&gpos[t], own);
  }
  __syncthreads();
#pragma unroll
  for (int j = 0; j < 16; ++j) {
    if (ok[j]) {
      int pos = lofs[bk[j]] + hcnt[wv][bk[j]] + rk[j];
      sp[pos] = py[j];
      sr[pos] = (unsigned short)rl[j];
      sb[pos] = (unsigned short)bk[j];
    }
  }
  __syncthreads();
#pragma unroll
  for (int j = 0; j < 16; ++j) {
    int pos = t + j * 256;
    if (pos < valid) {
      int b = sb[pos];
      int w = hbase[b] + (pos - lofs[b]);
      tmp4[w] = sp[pos];
      tmpr[w] = sr[pos];
    }
  }
}

// Launch 3: fused CSR finalize (blocks < kBuildBlocks) || ballot compact of
// the marked subset rows (tail; needs launch 2's mark_rows). Build part: TWO
// blocks per bucket; each block hists ONLY its 1024-row half (round-11
// half-hist: half-1's base = gpos[b] - own_half_total, the complement
// identity -> no full-bucket hist needed), scans it, writes FINAL rowptr for
// its rows, places its rows' edges via LDS cursors. Write windows are
// contiguous disjoint ~68 KB ranges -> single-XCD writer per cache line
// (round-7 lesson: multi-XCD partial lines = 15x write amplification).
__global__ __launch_bounds__(1024) void build_csr(
    const int* __restrict__ gpos, const int* __restrict__ tmp4,
    const unsigned short* __restrict__ tmpr, int* __restrict__ rowptr,
    int* __restrict__ edges, const int* __restrict__ mark,
    int* __restrict__ list, int* __restrict__ scnt) {
  int t = threadIdx.x;
  if ((int)blockIdx.x >= kBuildBlocks) {   // --- compact_rows tail (1024 thr) ---
    __shared__ int wbase[16];
    int i = ((int)blockIdx.x - kBuildBlocks) * 1024 + t;
    bool m = (i < kN) && mark[i];
    unsigned long long bal = __ballot(m);
    int wv = t >> 6, ln = t & 63;
    if (ln == 0) wbase[wv] = __popcll(bal);
    __syncthreads();
    if (t == 0) {
      int tot = 0;
#pragma unroll
      for (int w = 0; w < 16; ++w) tot += wbase[w];
      int p = tot ? atomicAdd(scnt, tot) : 0;
#pragma unroll
      for (int w = 0; w < 16; ++w) { int c = wbase[w]; wbase[w] = p; p += c; }
    }
    __syncthreads();
    if (m) {
      int rank = __popcll(bal & ((1ull << ln) - 1));
      list[wbase[wv] + rank] = i;
    }
    return;
  }
  // --- build part ---
  __shared__ int h[1024];            // half-hist -> global cursors
  __shared__ int lsum[256];
  __shared__ int gscan[256];
  int b = blockIdx.x >> 1;
  int half = blockIdx.x & 1;
  // bucket base: in-block inclusive scan of gpos[0..kNBKT) (147 values)
  if (t < 256) gscan[t] = (t < kNBKT) ? gpos[t] : 0;
  if (t < 1024) h[t] = 0;
  __syncthreads();
  for (int o = 1; o < 256; o <<= 1) {
    int v = 0;
    if (t < 256 && t >= o) v = gscan[t - o];
    __syncthreads();
    if (t < 256 && t >= o) gscan[t] += v;
    __syncthreads();
  }
  int bucket_base = (b == 0) ? 0 : gscan[b - 1];
  int s = b * kCap;
  int e = s + gpos[b];
  int lo = half << 10, hi = lo + 1024;
  // pass 1: histogram of THIS half's rows only
  for (int j = s + t; j < e; j += 1024) {
    int rl = tmpr[j];
    if (rl >= lo && rl < hi) atomicAdd(&h[rl - lo], 1);
  }
  __syncthreads();
  // scan 1024 rows (256 threads x 4), write FINAL rowptr, make cursors
  int cnt[4], pref[4];
  if (t < 256) {
    int acc = 0;
#pragma unroll
    for (int k = 0; k < 4; ++k) {
      cnt[k] = h[t * 4 + k];
      pref[k] = acc;
      acc += cnt[k];
    }
    lsum[t] = acc;
  }
  __syncthreads();
  for (int o = 1; o < 256; o <<= 1) {
    int v = 0;
    if (t < 256 && t >= o) v = lsum[t - o];
    __syncthreads();
    if (t < 256 && t >= o) lsum[t] += v;
    __syncthreads();
  }
  int base_local = half ? (gpos[b] - lsum[255]) : 0;   // complement identity
  if (t < 256) {
    int ex = (t == 0) ? 0 : lsum[t - 1];
#pragma unroll
    for (int k = 0; k < 4; ++k) {
      int g = bucket_base + base_local + ex + pref[k];
      int r = b * kRowsPerBkt + lo + t * 4 + k;
      if (r < kN) rowptr[r] = g;
      h[t * 4 + k] = g;                 // global write cursor
    }
  }
  if (blockIdx.x == 0 && t == 0) rowptr[kN] = kNNZ;
  __syncthreads();
  // pass 2: place only this half's rows via LDS cursors
  for (int j = s + t; j < e; j += 1024) {
    int rl = tmpr[j];
    if (rl >= lo && rl < hi) {
      int dst = atomicAdd(&h[rl - lo], 1);
      edges[dst] = tmp4[j];
    }
  }
}

// Reduction-free spmm, fp8 in / fp8 out (both scaled 64*true). One 8-lane
// group per row; lane l owns dims [8l,8l+8) = one 8-byte gather. Unroll-4
// edge prefetch. MODE 0: all rows, + mark_cols tail blocks (union subset
// rows' edge endpoints into mcmark for the layer-2 mask; consumed by the
// NEXT launch). MODE 1: rows with aux[r]!=0. MODE 2: rows from aux list.
// Identity row order for 0/1 (round-2 lesson). Round-6/8/9/10 counters:
// fetch-rate-bound ~3.65 TB/s, within ~10% of the 273 MB floor -> frozen.
template <int MODE>
__global__ __launch_bounds__(256, 8) void spmm(
    const int* __restrict__ rowptr, const int* __restrict__ edges,
    const unsigned char* __restrict__ x, unsigned char* __restrict__ yq,
    const int* __restrict__ aux, const int* __restrict__ cnt,
    int* __restrict__ mcmark) {
  if (MODE == 0 && (int)blockIdx.x >= kSpmmMain) {   // --- mark_cols tail ---
    int p = ((int)blockIdx.x - kSpmmMain) * 256 + threadIdx.x;
    if (p < *cnt) {
      int r = aux[p];
      int s = rowptr[r], e = rowptr[r + 1];
      for (int j = s; j < e; ++j) mcmark[edges[j] & 0x7FFFF] = 1;
    }
    return;
  }
  int t = threadIdx.x;
  int l = t & 7;                               // dim octet
  int wid = (blockIdx.x * 256 + t) >> 6;       // global wave id
  int g = (t >> 3) & 7;                        // group (row) within wave
  int p = wid * 8 + g;
  int r = -1;
  bool live = false;
  if (MODE == 2) {
    int n = *cnt;
    if (p < n) { r = aux[p]; live = true; }
  } else {
    if (p < kN) { r = p; live = (MODE == 0) || (aux[r] != 0); }
  }
  int s = 0, e = 0;
  if (live) { s = rowptr[r]; e = rowptr[r + 1]; }
  int mx = e - s;
#pragma unroll
  for (int m = 8; m <= 32; m <<= 1) mx = max(mx, __shfl_xor(mx, m, 64));
  float acc[8];
#pragma unroll
  for (int k = 0; k < 8; ++k) acc[k] = 0.f;
  int last = max(e - 1, 0);
  int j = s;
  int E0 = edges[min(j, last)];
  int E1 = edges[min(j + 1, last)];
  int E2 = edges[min(j + 2, last)];
  int E3 = edges[min(j + 3, last)];
  for (int it = 0; it < mx; it += 4) {
    float v0 = (j     < e) ? vdec(E0) : 0.f;
    float v1 = (j + 1 < e) ? vdec(E1) : 0.f;
    float v2 = (j + 2 < e) ? vdec(E2) : 0.f;
    float v3 = (j + 3 < e) ? vdec(E3) : 0.f;
    v2i h0 = ((const v2i*)(x + (size_t)(E0 & 0x7FFFF) * kD))[l];
    v2i h1 = ((const v2i*)(x + (size_t)(E1 & 0x7FFFF) * kD))[l];
    v2i h2 = ((const v2i*)(x + (size_t)(E2 & 0x7FFFF) * kD))[l];
    v2i h3 = ((const v2i*)(x + (size_t)(E3 & 0x7FFFF) * kD))[l];
    j += 4;
    E0 = edges[min(j, last)];                  // prefetch next quad (clamped)
    E1 = edges[min(j + 1, last)];
    E2 = edges[min(j + 2, last)];
    E3 = edges[min(j + 3, last)];
    float f[8];
    dec8(h0, f);
#pragma unroll
    for (int k = 0; k < 8; ++k) acc[k] = fmaf(v0, f[k], acc[k]);
    dec8(h1, f);
#pragma unroll
    for (int k = 0; k < 8; ++k) acc[k] = fmaf(v1, f[k], acc[k]);
    dec8(h2, f);
#pragma unroll
    for (int k = 0; k < 8; ++k) acc[k] = fmaf(v2, f[k], acc[k]);
    dec8(h3, f);
#pragma unroll
    for (int k = 0; k < 8; ++k) acc[k] = fmaf(v3, f[k], acc[k]);
  }
  if (live) {
    unsigned int w0 = 0, w1 = 0;
#pragma unroll
    for (int k = 0; k < 4; ++k) w0 |= (unsigned int)enc(acc[k]) << (8 * k);
#pragma unroll
    for (int k = 0; k < 4; ++k) w1 |= (unsigned int)enc(acc[4 + k]) << (8 * k);
    v2i o; o.x = (int)w0; o.y = (int)w1;
    ((v2i*)yq)[(size_t)r * 8 + l] = o;
  }
}

// out[b] = dot(emb_u + l1 + l2 + l3, emb_i + l1 + l2 + l3) / 16.
// Identical fp32 add order ((emb+l1)+l2)+l3 as the reference acc chain.
__global__ void finalize(const int* __restrict__ users, const int* __restrict__ items,
                         const float* __restrict__ uemb, const float* __restrict__ iemb,
                         const unsigned char* __restrict__ l1,
                         const unsigned char* __restrict__ l2,
                         const unsigned char* __restrict__ l3, float* __restrict__ out) {
  int tid = blockIdx.x * blockDim.x + threadIdx.x;
  if (tid >= kB * kD) return;
  int b = tid >> 6, d = tid & 63;
  size_t u = (size_t)users[b] * kD + d;
  size_t iw = (size_t)(kUsers + items[b]) * kD + d;
  float us = uemb[(size_t)users[b] * kD + d] + dec1(l1[u]) + dec1(l2[u]) + dec1(l3[u]);
  float vs = iemb[(size_t)items[b] * kD + d] + dec1(l1[iw]) + dec1(l2[iw]) + dec1(l3[iw]);
  float p = us * vs;
  for (int o = 32; o > 0; o >>= 1) p += __shfl_down(p, o, 64);
  if (d == 0) out[b] = p * 0.0625f;
}

}  // namespace

extern "C" void kernel_launch(void* const* d_in, const int* in_sizes, int n_in,
                              void* d_out, int out_size, void* d_ws, size_t ws_size,
                              hipStream_t stream) {
  const int*   users = (const int*)d_in[0];
  const int*   items = (const int*)d_in[1];
  const int*   erow  = (const int*)d_in[2];
  const int*   ecol  = (const int*)d_in[3];
  const float* evals = (const float*)d_in[4];
  const float* uemb  = (const float*)d_in[5];
  const float* iemb  = (const float*)d_in[6];
  float* out = (float*)d_out;

  char* ws = (char*)d_ws;
  size_t off = 0;
  auto take = [&](size_t bytes) -> char* {
    char* p = ws + off;
    off = (off + bytes + 255) & ~(size_t)255;
    return p;
  };
  int*    rowptr   = (int*)take((size_t)(kN + 1) * 4);
  int*    gpos     = (int*)take((kNBKT + 1) * 4);
  int*    mark     = (int*)take((size_t)kN * 4);
  int*    list     = (int*)take((size_t)kMaxSub * 4);
  int*    scnt     = (int*)take(256);
  int*    edges    = (int*)take((size_t)kNNZ * 4);                   // 20 MB packed
  int*    tmp4     = (int*)take((size_t)kNBKT * kCap * 4);           // 24 MB payload
  unsigned short* tmpr = (unsigned short*)take((size_t)kNBKT * kCap * 2);  // 12 MB rowlocal
  unsigned char* xq0 = (unsigned char*)take((size_t)kN * kD);        // emb, then l3
  unsigned char* xq1 = (unsigned char*)take((size_t)kN * kD);        // l1
  unsigned char* xq2 = (unsigned char*)take((size_t)kN * kD);        // l2
  (void)ws_size; (void)in_sizes; (void)n_in; (void)out_size;

  // --- 7 launches total (round-11: launch overhead ~8-10 us each) ---
  // 1: zero bookkeeping || fp8-convert embeddings
  prep<<<kZeroBlocks + kFp8Blocks, 256, 0, stream>>>(gpos, mark, scnt, uemb, iemb, xq0);
  // 2: bucket partition || mark subset rows
  bucket_scatter<<<kScatBlocks + kMarkBlocks, 256, 0, stream>>>(
      erow, ecol, evals, gpos, tmp4, tmpr, users, items, mark);
  // 3: CSR finalize (half-hist, single-XCD windows) || ballot-compact subset
  build_csr<<<kBuildBlocks + kCompBlocks, 1024, 0, stream>>>(
      gpos, tmp4, tmpr, rowptr, edges, mark, list, scnt);
  // 4-6: propagation xq0(emb)->xq1(l1)->xq2(l2,masked)->xq0(l3,subset);
  //      layer-1 launch also unions subset edge endpoints into mark
  spmm<0><<<kSpmmMain + kMCBlocks, 256, 0, stream>>>(rowptr, edges, xq0, xq1,
                                                     list, scnt, mark);
  spmm<1><<<kSpmmMain, 256, 0, stream>>>(rowptr, edges, xq1, xq2, mark, nullptr, nullptr);
  spmm<2><<<(kMaxSub + 31) / 32, 256, 0, stream>>>(rowptr, edges, xq2, xq0,
                                                   list, scnt, nullptr);
  // 7: gather + 3-layer sum + dot
  finalize<<<(kB * kD) / 256, 256, 0, stream>>>(users, items, uemb, iemb,
                                                xq1, xq2, xq0, out);
}